// Round 21
// baseline (1389.012 us; speedup 1.0000x reference)
//
#include <hip/hip_runtime.h>
#include <hip/hip_bf16.h>
#include <math.h>

#define T_LEN 4096
#define EMBD 1024
#define DH 128
#define NHASH 8
#define NHEADS 8
#define FLAG_CAP 65536
#define GAP_THRESH 1e-2f

typedef __attribute__((ext_vector_type(8))) short short8;
typedef __attribute__((ext_vector_type(16))) float f32x16;

// LDS swizzle: row-major [r][128] bf16, 16B-block XOR by (row&7) — G4 fix.
__device__ __forceinline__ int swz(int row, int col) {
    return (row << 7) + (col ^ ((row & 7) << 3));
}
__device__ __forceinline__ unsigned cvtpk(float lo, float hi) {
    unsigned r;
    asm("v_cvt_pk_bf16_f32 %0, %1, %2" : "=v"(r) : "v"(lo), "v"(hi));
    return r;
}
__device__ __forceinline__ float bfu_lo(unsigned u) {
    union { unsigned x; float f; } c; c.x = u << 16; return c.f;
}
__device__ __forceinline__ float bfu_hi(unsigned u) {
    union { unsigned x; float f; } c; c.x = u & 0xffff0000u; return c.f;
}
__device__ __forceinline__ float bfus2f(unsigned short s) {
    union { unsigned x; float f; } c; c.x = ((unsigned)s) << 16; return c.f;
}

// ------------------------------------------------------------------
// K1: WAVE-SPLIT merged projections. 512 threads, 8 rows/block,
// x staged ONCE. Waves 0-3 (tid<256): qk = x@w_qk (proven loop,
// acc[8][4] only -> no spill); waves 4-7: v = x@w_v. Emits qkh/qkl
// (hi/lo bf16 of qk), rsn, vb. Values identical to the proven
// separate kernels (same per-accumulator FMA order).
// ------------------------------------------------------------------
__global__ __launch_bounds__(512) void k_proj(
    const float* __restrict__ x, const float* __restrict__ wqk,
    const float* __restrict__ wv, __hip_bfloat16* __restrict__ qkh,
    __hip_bfloat16* __restrict__ qkl, float* __restrict__ rsn,
    __hip_bfloat16* __restrict__ vb)
{
    __shared__ float xs[8][EMBD];      // 32 KB
    const int row0 = blockIdx.x * 8;
    const int tid = threadIdx.x;       // 0..511
    const int ct = tid & 255;          // col group: cols 4ct..4ct+3
    const int half = tid >> 8;         // 0: qk, 1: v

    for (int u = tid; u < 8 * 256; u += 512) {
        int rr = u >> 8, q = u & 255;
        reinterpret_cast<float4*>(xs[rr])[q] =
            reinterpret_cast<const float4*>(x + (size_t)(row0 + rr) * EMBD)[q];
    }
    __syncthreads();

    float acc[8][4] = {};
    {
        const float* wp = (half ? wv : wqk) + 4 * ct;
        for (int e = 0; e < EMBD; ++e) {
            float4 w4 = *reinterpret_cast<const float4*>(wp + (size_t)e * EMBD);
            #pragma unroll
            for (int rr = 0; rr < 8; ++rr) {
                float xe = xs[rr][e];
                acc[rr][0] = fmaf(xe, w4.x, acc[rr][0]);
                acc[rr][1] = fmaf(xe, w4.y, acc[rr][1]);
                acc[rr][2] = fmaf(xe, w4.z, acc[rr][2]);
                acc[rr][3] = fmaf(xe, w4.w, acc[rr][3]);
            }
        }
    }
    const int j = 4 * ct;
    const int h = j >> 7, d = j & 127;
    if (half == 0) {
        #pragma unroll
        for (int rr = 0; rr < 8; ++rr) {
            float f0 = acc[rr][0], f1 = acc[rr][1], f2 = acc[rr][2], f3 = acc[rr][3];
            float ss = f0*f0 + f1*f1 + f2*f2 + f3*f3;
            #pragma unroll
            for (int m = 1; m < 32; m <<= 1) ss += __shfl_xor(ss, m);
            float rs = 1.0f / sqrtf(fmaxf(ss, 1e-12f));

            int row = row0 + rr;
            int b = row >> 12, t = row & 4095;
            size_t base = ((size_t)(b * NHEADS + h) * T_LEN + t) * DH + d;

            unsigned h01 = cvtpk(f0, f1), h23 = cvtpk(f2, f3);
            float l0 = f0 - bfu_lo(h01), l1 = f1 - bfu_hi(h01);
            float l2 = f2 - bfu_lo(h23), l3 = f3 - bfu_hi(h23);
            *reinterpret_cast<uint2*>(qkh + base) = make_uint2(h01, h23);
            *reinterpret_cast<uint2*>(qkl + base) = make_uint2(cvtpk(l0, l1), cvtpk(l2, l3));
            if ((ct & 31) == 0)
                rsn[(size_t)(b * NHEADS + h) * T_LEN + t] = rs;
        }
    } else {
        #pragma unroll
        for (int rr = 0; rr < 8; ++rr) {
            int row = row0 + rr;
            int b = row >> 12, t = row & 4095;
            *reinterpret_cast<uint2*>(vb + ((size_t)(b * NHEADS + h) * T_LEN + t) * DH + d)
                = make_uint2(cvtpk(acc[rr][0], acc[rr][1]), cvtpk(acc[rr][2], acc[rr][3]));
        }
    }
}

// ------------------------------------------------------------------
// K1b: LSH hash, ALL F32 with top-2 gap test (proven round 20).
// ------------------------------------------------------------------
__global__ __launch_bounds__(256) void k_hash2f(
    const __hip_bfloat16* __restrict__ qkh, const __hip_bfloat16* __restrict__ qkl,
    const float* __restrict__ rot, unsigned* __restrict__ bucketArr,
    unsigned* __restrict__ counter, unsigned* __restrict__ flaglist)
{
    __shared__ float qs[8][EMBD];      // 32 KB
    const int tok0 = blockIdx.x * 8;
    const int tid = threadIdx.x;
    const int j = 4 * tid;
    const int h = j >> 7, d = j & 127;

    #pragma unroll
    for (int tk = 0; tk < 8; ++tk) {
        int row = tok0 + tk;
        int b = row >> 12, t = row & 4095;
        size_t base = ((size_t)(b * NHEADS + h) * T_LEN + t) * DH + d;
        ushort4 h4 = *reinterpret_cast<const ushort4*>(qkh + base);
        ushort4 l4 = *reinterpret_cast<const ushort4*>(qkl + base);
        qs[tk][j + 0] = bfus2f(h4.x) + bfus2f(l4.x);
        qs[tk][j + 1] = bfus2f(h4.y) + bfus2f(l4.y);
        qs[tk][j + 2] = bfus2f(h4.z) + bfus2f(l4.z);
        qs[tk][j + 3] = bfus2f(h4.w) + bfus2f(l4.w);
    }
    __syncthreads();

    const int r = tid >> 5, i = tid & 31;
    const float* rp = rot + r * 32 + i;
    for (int hh = 0; hh < NHEADS; ++hh) {
        float acc[8] = {};
        for (int f = 0; f < DH; ++f) {
            float rv = rp[(size_t)f * 256];
            #pragma unroll
            for (int tk = 0; tk < 8; ++tk)
                acc[tk] = fmaf(qs[tk][hh * DH + f], rv, acc[tk]);
        }
        #pragma unroll
        for (int tk = 0; tk < 8; ++tk) {
            float v, v2; int idx;
            float a = acc[tk];
            if (a >= 0.0f) { v = a; idx = i; v2 = -a; }
            else           { v = -a; idx = i + 32; v2 = a; }
            #pragma unroll
            for (int m = 1; m < 32; m <<= 1) {
                float ov = __shfl_xor(v, m);
                int oi = __shfl_xor(idx, m);
                float ov2 = __shfl_xor(v2, m);
                bool owin = (ov > v) || (ov == v && oi < idx);
                float lv1 = owin ? v : ov;      // loser's top1
                float wv2 = owin ? ov2 : v2;    // winner's top2
                if (owin) { v = ov; idx = oi; }
                v2 = fmaxf(lv1, wv2);
            }
            if (i == 0) {
                int row = tok0 + tk;
                int b = row >> 12, t = row & 4095;
                int B = b * NHEADS + hh;
                bucketArr[((size_t)B * NHASH + r) * T_LEN + t] = (unsigned)idx;
                if (v - v2 < GAP_THRESH) {
                    unsigned p = atomicAdd(counter, 1u);
                    if (p < FLAG_CAP)
                        flaglist[p] = ((unsigned)B << 15) | ((unsigned)r << 12) | (unsigned)t;
                }
            }
        }
    }
}

// ------------------------------------------------------------------
// K1c: exact f64 fixup for flagged near-tie argmaxes (proven).
// ------------------------------------------------------------------
__global__ __launch_bounds__(128) void k_fixup(
    const float* __restrict__ x, const float* __restrict__ wqk,
    const float* __restrict__ rot, const unsigned* __restrict__ counter,
    const unsigned* __restrict__ flaglist, unsigned* __restrict__ bucketArr)
{
    __shared__ float xsf[EMBD];
    __shared__ double qk64[DH];
    __shared__ double vals[64];
    unsigned n = *counter;
    if (n > FLAG_CAP) n = FLAG_CAP;
    for (unsigned item = blockIdx.x; item < n; item += gridDim.x) {
        unsigned pk = flaglist[item];
        int t = pk & 4095, r = (pk >> 12) & 7, B = pk >> 15;
        int b = B >> 3, h = B & 7;
        for (int u = threadIdx.x; u < 256; u += 128)
            reinterpret_cast<float4*>(xsf)[u] =
                reinterpret_cast<const float4*>(x + (size_t)(b * T_LEN + t) * EMBD)[u];
        __syncthreads();
        {
            double a = 0.0;
            const float* wp = wqk + h * DH + threadIdx.x;
            for (int e = 0; e < EMBD; ++e)
                a = fma((double)xsf[e], (double)wp[(size_t)e * EMBD], a);
            qk64[threadIdx.x] = a;
        }
        __syncthreads();
        if (threadIdx.x < 32) {
            const float* rp = rot + r * 32 + threadIdx.x;
            double acc2 = 0.0;
            for (int f = 0; f < DH; ++f)
                acc2 = fma(qk64[f], (double)rp[(size_t)f * 256], acc2);
            vals[threadIdx.x] = acc2;
            vals[threadIdx.x + 32] = -acc2;
        }
        __syncthreads();
        if (threadIdx.x == 0) {
            double best = vals[0]; int bi = 0;
            for (int u = 1; u < 64; ++u)
                if (vals[u] > best) { best = vals[u]; bi = u; }
            bucketArr[((size_t)B * NHASH + r) * T_LEN + t] = (unsigned)bi;
        }
        __syncthreads();
    }
}

// ------------------------------------------------------------------
// K3: stable counting sort per (B, hash-round) — unchanged (proven).
// ------------------------------------------------------------------
__global__ __launch_bounds__(64) void k_sort(
    const unsigned* __restrict__ bucketArr, unsigned* __restrict__ st)
{
    __shared__ unsigned short bkt[T_LEN];
    __shared__ unsigned hist[64][64];
    __shared__ unsigned bstart[64];
    const int B = blockIdx.x >> 3, r = blockIdx.x & 7;
    const unsigned* src = bucketArr + ((size_t)B * NHASH + r) * T_LEN;
    const int tid = threadIdx.x;

    for (int k = tid; k < T_LEN; k += 64) bkt[k] = (unsigned short)src[k];
    for (int k = tid; k < 64 * 64; k += 64) (&hist[0][0])[k] = 0;
    __syncthreads();
    {
        const int base = tid * 64;
        for (int k = 0; k < 64; ++k) hist[tid][bkt[base + k]]++;
    }
    __syncthreads();
    {
        unsigned tot = 0;
        for (int c = 0; c < 64; ++c) tot += hist[c][tid];
        bstart[tid] = tot;
    }
    __syncthreads();
    if (tid == 0) {
        unsigned run = 0;
        for (int q = 0; q < 64; ++q) { unsigned c = bstart[q]; bstart[q] = run; run += c; }
    }
    __syncthreads();
    {
        unsigned run = bstart[tid];
        for (int c = 0; c < 64; ++c) { unsigned h = hist[c][tid]; hist[c][tid] = run; run += h; }
    }
    __syncthreads();
    {
        unsigned* dst = st + ((size_t)B * NHASH + r) * T_LEN;
        const int base = tid * 64;
        for (int k = 0; k < 64; ++k) {
            unsigned bb2 = bkt[base + k];
            unsigned p = hist[tid][bb2]++;
            dst[p] = (unsigned)(base + k);
        }
    }
}

// ------------------------------------------------------------------
// K4: per-bin attention, ONE PASS per hash round — unchanged (proven).
// ------------------------------------------------------------------
__global__ __launch_bounds__(256, 3) void k_bin_pv(
    const __hip_bfloat16* __restrict__ qkh, const __hip_bfloat16* __restrict__ qkl,
    const __hip_bfloat16* __restrict__ vb, const float* __restrict__ rsn,
    const unsigned* __restrict__ st, float* __restrict__ Mbuf,
    float* __restrict__ Sbuf, float* __restrict__ attn, int rnd)
{
    __shared__ short Kh[128 * 128];        // K_hi -> V^T -> osc f32[64][128]
    __shared__ unsigned short Pb[64 * 128];// P bf16: [(j>>1)][i][j&1], 16 KB
    __shared__ int ktok[128];
    __shared__ float rs_l[128];
    __shared__ float red4b[2][2][2][32];   // [it][jt2][h5][col]
    __shared__ float mrow[64];
    __shared__ float abrow[64][2];         // per-query (a, b) weights

    const int tid = threadIdx.x;
    const int c = blockIdx.x & 63;
    const int B = blockIdx.x >> 6;
    const unsigned* stp = st + ((size_t)B * NHASH + rnd) * T_LEN;

    if (tid < 128) {
        int cc = (tid < 64) ? c : (c == 0 ? 1 : c - 1);
        int tok = (int)stp[cc * 64 + (tid & 63)];
        ktok[tid] = tok;
        rs_l[tid] = rsn[(size_t)B * T_LEN + tok];
    }
    __syncthreads();

    // stage K_hi (swizzled)
    for (int u = tid; u < 128 * 16; u += 256) {
        int row = u >> 4, blk = u & 15;
        *reinterpret_cast<int4*>(&Kh[swz(row, blk * 8)]) =
            *reinterpret_cast<const int4*>(qkh + ((size_t)B * T_LEN + ktok[row]) * DH + blk * 8);
    }

    const int wave = tid >> 6, lane = tid & 63;
    const int it = wave & 1, jt2 = wave >> 1;
    const int h5 = lane >> 5;
    const int i_loc = it * 32 + (lane & 31);
    const int qtok_i = ktok[i_loc];
    short8 qfh[8], qfl[8];
    {
        size_t qoff = ((size_t)B * T_LEN + qtok_i) * DH + (h5 << 3);
        #pragma unroll
        for (int kt = 0; kt < 8; ++kt) {
            qfh[kt] = *reinterpret_cast<const short8*>(qkh + qoff + kt * 16);
            qfl[kt] = *reinterpret_cast<const short8*>(qkl + qoff + kt * 16);
        }
    }
    __syncthreads();

    const float scale = 0.08838834764831845f;
    float p2[2][16];   // raw masked dots, then P
    #pragma unroll
    for (int jj = 0; jj < 2; ++jj) {
        int jt = jt2 * 2 + jj;
        f32x16 acc = {};
        #pragma unroll
        for (int kt = 0; kt < 8; ++kt) {        // FULL K, 2-term split S
            int so = swz(jt * 32 + (lane & 31), kt * 16 + (h5 << 3));
            short8 afh = *reinterpret_cast<const short8*>(&Kh[so]);
            acc = __builtin_amdgcn_mfma_f32_32x32x16_bf16(afh, qfh[kt], acc, 0, 0, 0);
            acc = __builtin_amdgcn_mfma_f32_32x32x16_bf16(afh, qfl[kt], acc, 0, 0, 0);
        }
        #pragma unroll
        for (int r2 = 0; r2 < 16; ++r2) {
            int jl = (r2 & 3) + ((r2 >> 2) << 3) + (h5 << 2);
            int jf = jt * 32 + jl;
            float s = acc[r2] * (scale * rs_l[jf]);
            p2[jj][r2] = (ktok[jf] == qtok_i) ? -1e5f : s;
        }
    }

    // ---- per-query max over 128 keys ----
    float mloc = p2[0][0];
    #pragma unroll
    for (int jj = 0; jj < 2; ++jj)
        #pragma unroll
        for (int r2 = 0; r2 < 16; ++r2) mloc = fmaxf(mloc, p2[jj][r2]);
    red4b[it][jt2][h5][lane & 31] = mloc;
    __syncthreads();                       // also: all Kh dot-reads done
    if (tid < 64) {
        int it2 = tid >> 5, i = tid & 31;
        mrow[tid] = fmaxf(fmaxf(red4b[it2][0][0][i], red4b[it2][0][1][i]),
                          fmaxf(red4b[it2][1][0][i], red4b[it2][1][1][i]));
    }
    __syncthreads();

    // ---- P = exp(S - m); per-query sum ----
    const float mi = mrow[i_loc];
    float sloc = 0.f;
    #pragma unroll
    for (int jj = 0; jj < 2; ++jj)
        #pragma unroll
        for (int r2 = 0; r2 < 16; ++r2) {
            float p = __expf(p2[jj][r2] - mi);
            p2[jj][r2] = p;
            sloc += p;
        }
    red4b[it][jt2][h5][lane & 31] = sloc;
    __syncthreads();

    // ---- s-merge + global M/S update; write Pb; stage V^T into Kh ----
    if (tid < 64) {
        int it2 = tid >> 5, i = tid & 31;
        float sr = red4b[it2][0][0][i] + red4b[it2][0][1][i] +
                   red4b[it2][1][0][i] + red4b[it2][1][1][i];
        float m = mrow[tid];
        size_t gi = (size_t)B * T_LEN + ktok[tid];
        float aw, bw;
        if (rnd == 0) {
            Mbuf[gi] = m; Sbuf[gi] = sr;
            aw = 0.f; bw = 1.f;
        } else {
            float Mold = Mbuf[gi];
            float Mnew = fmaxf(Mold, m);
            aw = __expf(Mold - Mnew);
            bw = __expf(m - Mnew);
            Sbuf[gi] = Sbuf[gi] * aw + sr * bw;
            Mbuf[gi] = Mnew;
        }
        abrow[tid][0] = aw; abrow[tid][1] = bw;
    }
    // P -> bf16 pairs: quadruple q covers rows 8q+4h5+{0..3} at col i_loc
    #pragma unroll
    for (int jj = 0; jj < 2; ++jj) {
        int jt = jt2 * 2 + jj;
        #pragma unroll
        for (int q = 0; q < 4; ++q) {
            int jhalf = jt * 16 + 4 * q + 2 * h5;   // (row>>1), row even
            unsigned pk0 = cvtpk(p2[jj][4 * q + 0], p2[jj][4 * q + 1]);
            unsigned pk1 = cvtpk(p2[jj][4 * q + 2], p2[jj][4 * q + 3]);
            *reinterpret_cast<unsigned*>(&Pb[jhalf * 128 + i_loc * 2]) = pk0;
            *reinterpret_cast<unsigned*>(&Pb[(jhalf + 1) * 128 + i_loc * 2]) = pk1;
        }
    }
    // restage Kh region as V^T (swizzled rows of V^T: row=d, col=j)
    {
        int j2 = tid >> 1, dbase = (tid & 1) * 64;
        const __hip_bfloat16* vrow = vb + ((size_t)B * T_LEN + ktok[j2]) * DH + dbase;
        #pragma unroll
        for (int mch = 0; mch < 8; ++mch) {
            short8 vv = *reinterpret_cast<const short8*>(vrow + mch * 8);
            #pragma unroll
            for (int e = 0; e < 8; ++e)
                Kh[swz(dbase + mch * 8 + e, j2)] = vv[e];
        }
    }
    __syncthreads();

    // MFMA PV: B-frags read directly from Pb (4 u32 each); A = V^T tiles.
    f32x16 oacc[4] = {};
    #pragma unroll
    for (int jj = 0; jj < 2; ++jj) {
        int jt = jt2 * 2 + jj;
        #pragma unroll
        for (int ks = 0; ks < 2; ++ks) {
            int jb0 = jt * 32 + ks * 16 + h5 * 8;   // even
            union Pack { unsigned u[4]; short8 v; } ph;
            #pragma unroll
            for (int m = 0; m < 4; ++m)
                ph.u[m] = *reinterpret_cast<const unsigned*>(
                    &Pb[((jb0 >> 1) + m) * 128 + i_loc * 2]);
            #pragma unroll
            for (int dt = 0; dt < 4; ++dt) {
                short8 af = *reinterpret_cast<const short8*>(
                    &Kh[swz(dt * 32 + (lane & 31), jb0)]);
                oacc[dt] = __builtin_amdgcn_mfma_f32_32x32x16_bf16(af, ph.v, oacc[dt], 0, 0, 0);
            }
        }
    }
    __syncthreads();   // done reading Pb and V^T(Kh)

    // combine jt2 halves in osc[64][128] f32 (Kh region, XOR-swizzled)
    float* osc = reinterpret_cast<float*>(Kh);
    if (jt2 == 1) {
        #pragma unroll
        for (int dt = 0; dt < 4; ++dt)
            #pragma unroll
            for (int r2 = 0; r2 < 16; ++r2) {
                int d = dt * 32 + (r2 & 3) + ((r2 >> 2) << 3) + (h5 << 2);
                osc[i_loc * 128 + (d ^ (i_loc & 28))] = oacc[dt][r2];
            }
    }
    __syncthreads();
    if (jt2 == 0) {
        #pragma unroll
        for (int dt = 0; dt < 4; ++dt)
            #pragma unroll
            for (int r2 = 0; r2 < 16; ++r2) {
                int d = dt * 32 + (r2 & 3) + ((r2 >> 2) << 3) + (h5 << 2);
                int a = i_loc * 128 + (d ^ (i_loc & 28));
                osc[a] += oacc[dt][r2];
            }
    }
    __syncthreads();

    // online-combined write: rnd 0 stores o_r; rnd>0: attn*a + o_r*b.
    #pragma unroll
    for (int w = 0; w < 8; ++w) {
        int lin = w * 256 + tid;          // float4 index over 64×32
        int rowq = lin >> 5;
        int d0 = (lin & 31) * 4;
        float4 sv4 = *reinterpret_cast<float4*>(&osc[rowq * 128 + (d0 ^ (rowq & 28))]);
        float* gp = attn + ((size_t)B * T_LEN + ktok[rowq]) * DH + d0;
        if (rnd == 0) {
            *reinterpret_cast<float4*>(gp) = sv4;
        } else {
            float aw = abrow[rowq][0], bw = abrow[rowq][1];
            float4 g = *reinterpret_cast<float4*>(gp);
            g.x = g.x * aw + sv4.x * bw;
            g.y = g.y * aw + sv4.y * bw;
            g.z = g.z * aw + sv4.z * bw;
            g.w = g.w * aw + sv4.w * bw;
            *reinterpret_cast<float4*>(gp) = g;
        }
    }
}

// ------------------------------------------------------------------
// K6: out = un-merge-heads(attn / S) @ w_out + b_out, 8 rows/block.
// ------------------------------------------------------------------
__global__ __launch_bounds__(256) void k_out(
    const float* __restrict__ attn, const float* __restrict__ Sbuf,
    const float* __restrict__ wout, const float* __restrict__ bout,
    float* __restrict__ out)
{
    __shared__ float as_[8][EMBD];     // 32 KB
    const int row0 = blockIdx.x * 8;
    const int tid = threadIdx.x;
    #pragma unroll
    for (int rr = 0; rr < 8; ++rr) {
        int row = row0 + rr;
        int b = row >> 12, t = row & 4095;
        for (int u = tid; u < EMBD; u += 256) {
            int h = u >> 7, d = u & 127;
            size_t gi = (size_t)(b * NHEADS + h) * T_LEN + t;
            as_[rr][u] = attn[gi * DH + d] / Sbuf[gi];
        }
    }
    __syncthreads();
    float acc[8][4] = {};
    const float* wp = wout + 4 * tid;
    for (int e = 0; e < EMBD; ++e) {
        float4 w4 = *reinterpret_cast<const float4*>(wp + (size_t)e * EMBD);
        #pragma unroll
        for (int rr = 0; rr < 8; ++rr) {
            float xe = as_[rr][e];
            acc[rr][0] = fmaf(xe, w4.x, acc[rr][0]);
            acc[rr][1] = fmaf(xe, w4.y, acc[rr][1]);
            acc[rr][2] = fmaf(xe, w4.z, acc[rr][2]);
            acc[rr][3] = fmaf(xe, w4.w, acc[rr][3]);
        }
    }
    int j = 4 * tid;
    float b0 = bout[j + 0], b1 = bout[j + 1], b2 = bout[j + 2], b3 = bout[j + 3];
    #pragma unroll
    for (int rr = 0; rr < 8; ++rr) {
        float4 o;
        o.x = acc[rr][0] + b0; o.y = acc[rr][1] + b1;
        o.z = acc[rr][2] + b2; o.w = acc[rr][3] + b3;
        *reinterpret_cast<float4*>(out + (size_t)(row0 + rr) * EMBD + j) = o;
    }
}

// ------------------------------------------------------------------
extern "C" void kernel_launch(void* const* d_in, const int* in_sizes, int n_in,
                              void* d_out, int out_size, void* d_ws, size_t ws_size,
                              hipStream_t stream)
{
    const float* x    = (const float*)d_in[0];
    const float* wqk  = (const float*)d_in[1];
    const float* wv   = (const float*)d_in[2];
    const float* wout = (const float*)d_in[3];
    const float* bout = (const float*)d_in[4];
    const float* rot  = (const float*)d_in[5];
    float* out = (float*)d_out;

    char* ws = (char*)d_ws;
    __hip_bfloat16* qkh       = (__hip_bfloat16*)(ws);              // 16.8 MB
    __hip_bfloat16* qkl       = (__hip_bfloat16*)(ws + 16777216);   // 16.8 MB
    __hip_bfloat16* vb        = (__hip_bfloat16*)(ws + 33554432);   // 16.8 MB
    float*          attn      = (float*)        (ws + 50331648);    // 33.5 MB
    unsigned*       bucketArr = (unsigned*)     (ws + 83886080);    //  2.1 MB
    unsigned*       st        = (unsigned*)     (ws + 85983232);    //  2.1 MB
    float*          Mbuf      = (float*)        (ws + 88080384);
    float*          Sbuf      = (float*)        (ws + 88342528);
    float*          rsn       = (float*)        (ws + 90439680);
    unsigned*       counter   = (unsigned*)     (ws + 90701824);
    unsigned*       flaglist  = (unsigned*)     (ws + 90705920);    // 256 KB

    hipMemsetAsync(counter, 0, 4, stream);
    k_proj<<<1024, 512, 0, stream>>>(x, wqk, wv, qkh, qkl, rsn, vb);
    k_hash2f<<<1024, 256, 0, stream>>>(qkh, qkl, rot, bucketArr, counter, flaglist);
    k_fixup<<<256, 128, 0, stream>>>(x, wqk, rot, counter, flaglist, bucketArr);
    k_sort<<<128, 64, 0, stream>>>(bucketArr, st);
    for (int r = 0; r < NHASH; ++r)
        k_bin_pv<<<1024, 256, 0, stream>>>(qkh, qkl, vb, rsn, st, Mbuf, Sbuf, attn, r);
    k_out<<<1024, 256, 0, stream>>>(attn, Sbuf, wout, bout, out);
}

// Round 22
// 1318.523 us; speedup vs baseline: 1.0535x; 1.0535x over previous
//
#include <hip/hip_runtime.h>
#include <hip/hip_bf16.h>
#include <math.h>

#define T_LEN 4096
#define EMBD 1024
#define DH 128
#define NHASH 8
#define NHEADS 8
#define FLAG_CAP 65536
#define GAP_THRESH 1e-2f

typedef __attribute__((ext_vector_type(8))) short short8;
typedef __attribute__((ext_vector_type(16))) float f32x16;

// LDS swizzle: row-major [r][128] bf16, 16B-block XOR by (row&7) — G4 fix.
__device__ __forceinline__ int swz(int row, int col) {
    return (row << 7) + (col ^ ((row & 7) << 3));
}
__device__ __forceinline__ unsigned cvtpk(float lo, float hi) {
    unsigned r;
    asm("v_cvt_pk_bf16_f32 %0, %1, %2" : "=v"(r) : "v"(lo), "v"(hi));
    return r;
}
__device__ __forceinline__ float bfu_lo(unsigned u) {
    union { unsigned x; float f; } c; c.x = u << 16; return c.f;
}
__device__ __forceinline__ float bfu_hi(unsigned u) {
    union { unsigned x; float f; } c; c.x = u & 0xffff0000u; return c.f;
}
__device__ __forceinline__ float bfus2f(unsigned short s) {
    union { unsigned x; float f; } c; c.x = ((unsigned)s) << 16; return c.f;
}

// ------------------------------------------------------------------
// K1a: qk = x @ w_qk in f32, 8 rows/block (r19-proven form).
// Emits qkh/qkl (hi/lo bf16 of qk) + rsn.
// ------------------------------------------------------------------
__global__ __launch_bounds__(256) void k_qk_gemm32(
    const float* __restrict__ x, const float* __restrict__ wqk,
    __hip_bfloat16* __restrict__ qkh, __hip_bfloat16* __restrict__ qkl,
    float* __restrict__ rsn)
{
    __shared__ float xs[8][EMBD];      // 32 KB
    const int row0 = blockIdx.x * 8;
    const int tid = threadIdx.x;
    #pragma unroll
    for (int rr = 0; rr < 8; ++rr)
        reinterpret_cast<float4*>(xs[rr])[tid] =
            reinterpret_cast<const float4*>(x + (size_t)(row0 + rr) * EMBD)[tid];
    __syncthreads();

    float acc[8][4] = {};
    const float* wp = wqk + 4 * tid;
    for (int e = 0; e < EMBD; ++e) {
        float4 w4 = *reinterpret_cast<const float4*>(wp + (size_t)e * EMBD);
        #pragma unroll
        for (int rr = 0; rr < 8; ++rr) {
            float xe = xs[rr][e];
            acc[rr][0] = fmaf(xe, w4.x, acc[rr][0]);
            acc[rr][1] = fmaf(xe, w4.y, acc[rr][1]);
            acc[rr][2] = fmaf(xe, w4.z, acc[rr][2]);
            acc[rr][3] = fmaf(xe, w4.w, acc[rr][3]);
        }
    }
    const int j = 4 * tid;
    const int h = j >> 7, d = j & 127;
    #pragma unroll
    for (int rr = 0; rr < 8; ++rr) {
        float f0 = acc[rr][0], f1 = acc[rr][1], f2 = acc[rr][2], f3 = acc[rr][3];
        float ss = f0*f0 + f1*f1 + f2*f2 + f3*f3;
        #pragma unroll
        for (int m = 1; m < 32; m <<= 1) ss += __shfl_xor(ss, m);
        float rs = 1.0f / sqrtf(fmaxf(ss, 1e-12f));

        int row = row0 + rr;
        int b = row >> 12, t = row & 4095;
        size_t base = ((size_t)(b * NHEADS + h) * T_LEN + t) * DH + d;

        unsigned h01 = cvtpk(f0, f1), h23 = cvtpk(f2, f3);
        float l0 = f0 - bfu_lo(h01), l1 = f1 - bfu_hi(h01);
        float l2 = f2 - bfu_lo(h23), l3 = f3 - bfu_hi(h23);
        *reinterpret_cast<uint2*>(qkh + base) = make_uint2(h01, h23);
        *reinterpret_cast<uint2*>(qkl + base) = make_uint2(cvtpk(l0, l1), cvtpk(l2, l3));
        if ((tid & 31) == 0)
            rsn[(size_t)(b * NHEADS + h) * T_LEN + t] = rs;
    }
}

// ------------------------------------------------------------------
// K2: v = x @ w_v, 8 rows/block -> v_bf16 (proven).
// ------------------------------------------------------------------
__global__ __launch_bounds__(256) void k_vproj(
    const float* __restrict__ x, const float* __restrict__ wv,
    __hip_bfloat16* __restrict__ vb)
{
    __shared__ float xs[8][EMBD];      // 32 KB
    const int row0 = blockIdx.x * 8;
    const int tid = threadIdx.x;
    #pragma unroll
    for (int rr = 0; rr < 8; ++rr)
        reinterpret_cast<float4*>(xs[rr])[tid] =
            reinterpret_cast<const float4*>(x + (size_t)(row0 + rr) * EMBD)[tid];
    __syncthreads();

    float acc[8][4] = {};
    const float* wp = wv + 4 * tid;
    for (int e = 0; e < EMBD; ++e) {
        float4 w4 = *reinterpret_cast<const float4*>(wp + (size_t)e * EMBD);
        #pragma unroll
        for (int rr = 0; rr < 8; ++rr) {
            float xe = xs[rr][e];
            acc[rr][0] = fmaf(xe, w4.x, acc[rr][0]);
            acc[rr][1] = fmaf(xe, w4.y, acc[rr][1]);
            acc[rr][2] = fmaf(xe, w4.z, acc[rr][2]);
            acc[rr][3] = fmaf(xe, w4.w, acc[rr][3]);
        }
    }
    int j = 4 * tid;
    int h = j >> 7, d = j & 127;
    #pragma unroll
    for (int rr = 0; rr < 8; ++rr) {
        int row = row0 + rr;
        int b = row >> 12, t = row & 4095;
        *reinterpret_cast<uint2*>(vb + ((size_t)(b * NHEADS + h) * T_LEN + t) * DH + d)
            = make_uint2(cvtpk(acc[rr][0], acc[rr][1]), cvtpk(acc[rr][2], acc[rr][3]));
    }
}

// ------------------------------------------------------------------
// K1b: LSH hash, ALL F32 with top-2 gap test (proven round 20).
// ------------------------------------------------------------------
__global__ __launch_bounds__(256) void k_hash2f(
    const __hip_bfloat16* __restrict__ qkh, const __hip_bfloat16* __restrict__ qkl,
    const float* __restrict__ rot, unsigned* __restrict__ bucketArr,
    unsigned* __restrict__ counter, unsigned* __restrict__ flaglist)
{
    __shared__ float qs[8][EMBD];      // 32 KB
    const int tok0 = blockIdx.x * 8;
    const int tid = threadIdx.x;
    const int j = 4 * tid;
    const int h = j >> 7, d = j & 127;

    #pragma unroll
    for (int tk = 0; tk < 8; ++tk) {
        int row = tok0 + tk;
        int b = row >> 12, t = row & 4095;
        size_t base = ((size_t)(b * NHEADS + h) * T_LEN + t) * DH + d;
        ushort4 h4 = *reinterpret_cast<const ushort4*>(qkh + base);
        ushort4 l4 = *reinterpret_cast<const ushort4*>(qkl + base);
        qs[tk][j + 0] = bfus2f(h4.x) + bfus2f(l4.x);
        qs[tk][j + 1] = bfus2f(h4.y) + bfus2f(l4.y);
        qs[tk][j + 2] = bfus2f(h4.z) + bfus2f(l4.z);
        qs[tk][j + 3] = bfus2f(h4.w) + bfus2f(l4.w);
    }
    __syncthreads();

    const int r = tid >> 5, i = tid & 31;
    const float* rp = rot + r * 32 + i;
    for (int hh = 0; hh < NHEADS; ++hh) {
        float acc[8] = {};
        for (int f = 0; f < DH; ++f) {
            float rv = rp[(size_t)f * 256];
            #pragma unroll
            for (int tk = 0; tk < 8; ++tk)
                acc[tk] = fmaf(qs[tk][hh * DH + f], rv, acc[tk]);
        }
        #pragma unroll
        for (int tk = 0; tk < 8; ++tk) {
            float v, v2; int idx;
            float a = acc[tk];
            if (a >= 0.0f) { v = a; idx = i; v2 = -a; }
            else           { v = -a; idx = i + 32; v2 = a; }
            #pragma unroll
            for (int m = 1; m < 32; m <<= 1) {
                float ov = __shfl_xor(v, m);
                int oi = __shfl_xor(idx, m);
                float ov2 = __shfl_xor(v2, m);
                bool owin = (ov > v) || (ov == v && oi < idx);
                float lv1 = owin ? v : ov;      // loser's top1
                float wv2 = owin ? ov2 : v2;    // winner's top2
                if (owin) { v = ov; idx = oi; }
                v2 = fmaxf(lv1, wv2);
            }
            if (i == 0) {
                int row = tok0 + tk;
                int b = row >> 12, t = row & 4095;
                int B = b * NHEADS + hh;
                bucketArr[((size_t)B * NHASH + r) * T_LEN + t] = (unsigned)idx;
                if (v - v2 < GAP_THRESH) {
                    unsigned p = atomicAdd(counter, 1u);
                    if (p < FLAG_CAP)
                        flaglist[p] = ((unsigned)B << 15) | ((unsigned)r << 12) | (unsigned)t;
                }
            }
        }
    }
}

// ------------------------------------------------------------------
// K1c: exact f64 fixup for flagged near-tie argmaxes (proven).
// ------------------------------------------------------------------
__global__ __launch_bounds__(128) void k_fixup(
    const float* __restrict__ x, const float* __restrict__ wqk,
    const float* __restrict__ rot, const unsigned* __restrict__ counter,
    const unsigned* __restrict__ flaglist, unsigned* __restrict__ bucketArr)
{
    __shared__ float xsf[EMBD];
    __shared__ double qk64[DH];
    __shared__ double vals[64];
    unsigned n = *counter;
    if (n > FLAG_CAP) n = FLAG_CAP;
    for (unsigned item = blockIdx.x; item < n; item += gridDim.x) {
        unsigned pk = flaglist[item];
        int t = pk & 4095, r = (pk >> 12) & 7, B = pk >> 15;
        int b = B >> 3, h = B & 7;
        for (int u = threadIdx.x; u < 256; u += 128)
            reinterpret_cast<float4*>(xsf)[u] =
                reinterpret_cast<const float4*>(x + (size_t)(b * T_LEN + t) * EMBD)[u];
        __syncthreads();
        {
            double a = 0.0;
            const float* wp = wqk + h * DH + threadIdx.x;
            for (int e = 0; e < EMBD; ++e)
                a = fma((double)xsf[e], (double)wp[(size_t)e * EMBD], a);
            qk64[threadIdx.x] = a;
        }
        __syncthreads();
        if (threadIdx.x < 32) {
            const float* rp = rot + r * 32 + threadIdx.x;
            double acc2 = 0.0;
            for (int f = 0; f < DH; ++f)
                acc2 = fma(qk64[f], (double)rp[(size_t)f * 256], acc2);
            vals[threadIdx.x] = acc2;
            vals[threadIdx.x + 32] = -acc2;
        }
        __syncthreads();
        if (threadIdx.x == 0) {
            double best = vals[0]; int bi = 0;
            for (int u = 1; u < 64; ++u)
                if (vals[u] > best) { best = vals[u]; bi = u; }
            bucketArr[((size_t)B * NHASH + r) * T_LEN + t] = (unsigned)bi;
        }
        __syncthreads();
    }
}

// ------------------------------------------------------------------
// K3: stable counting sort per (B, hash-round) — unchanged (proven).
// ------------------------------------------------------------------
__global__ __launch_bounds__(64) void k_sort(
    const unsigned* __restrict__ bucketArr, unsigned* __restrict__ st)
{
    __shared__ unsigned short bkt[T_LEN];
    __shared__ unsigned hist[64][64];
    __shared__ unsigned bstart[64];
    const int B = blockIdx.x >> 3, r = blockIdx.x & 7;
    const unsigned* src = bucketArr + ((size_t)B * NHASH + r) * T_LEN;
    const int tid = threadIdx.x;

    for (int k = tid; k < T_LEN; k += 64) bkt[k] = (unsigned short)src[k];
    for (int k = tid; k < 64 * 64; k += 64) (&hist[0][0])[k] = 0;
    __syncthreads();
    {
        const int base = tid * 64;
        for (int k = 0; k < 64; ++k) hist[tid][bkt[base + k]]++;
    }
    __syncthreads();
    {
        unsigned tot = 0;
        for (int c = 0; c < 64; ++c) tot += hist[c][tid];
        bstart[tid] = tot;
    }
    __syncthreads();
    if (tid == 0) {
        unsigned run = 0;
        for (int q = 0; q < 64; ++q) { unsigned c = bstart[q]; bstart[q] = run; run += c; }
    }
    __syncthreads();
    {
        unsigned run = bstart[tid];
        for (int c = 0; c < 64; ++c) { unsigned h = hist[c][tid]; hist[c][tid] = run; run += h; }
    }
    __syncthreads();
    {
        unsigned* dst = st + ((size_t)B * NHASH + r) * T_LEN;
        const int base = tid * 64;
        for (int k = 0; k < 64; ++k) {
            unsigned bb2 = bkt[base + k];
            unsigned p = hist[tid][bb2]++;
            dst[p] = (unsigned)(base + k);
        }
    }
}

// ------------------------------------------------------------------
// K4: per-bin attention, ONE PASS per hash round — unchanged (proven).
// ------------------------------------------------------------------
__global__ __launch_bounds__(256, 3) void k_bin_pv(
    const __hip_bfloat16* __restrict__ qkh, const __hip_bfloat16* __restrict__ qkl,
    const __hip_bfloat16* __restrict__ vb, const float* __restrict__ rsn,
    const unsigned* __restrict__ st, float* __restrict__ Mbuf,
    float* __restrict__ Sbuf, float* __restrict__ attn, int rnd)
{
    __shared__ short Kh[128 * 128];        // K_hi -> V^T -> osc f32[64][128]
    __shared__ unsigned short Pb[64 * 128];// P bf16: [(j>>1)][i][j&1], 16 KB
    __shared__ int ktok[128];
    __shared__ float rs_l[128];
    __shared__ float red4b[2][2][2][32];   // [it][jt2][h5][col]
    __shared__ float mrow[64];
    __shared__ float abrow[64][2];         // per-query (a, b) weights

    const int tid = threadIdx.x;
    const int c = blockIdx.x & 63;
    const int B = blockIdx.x >> 6;
    const unsigned* stp = st + ((size_t)B * NHASH + rnd) * T_LEN;

    if (tid < 128) {
        int cc = (tid < 64) ? c : (c == 0 ? 1 : c - 1);
        int tok = (int)stp[cc * 64 + (tid & 63)];
        ktok[tid] = tok;
        rs_l[tid] = rsn[(size_t)B * T_LEN + tok];
    }
    __syncthreads();

    // stage K_hi (swizzled)
    for (int u = tid; u < 128 * 16; u += 256) {
        int row = u >> 4, blk = u & 15;
        *reinterpret_cast<int4*>(&Kh[swz(row, blk * 8)]) =
            *reinterpret_cast<const int4*>(qkh + ((size_t)B * T_LEN + ktok[row]) * DH + blk * 8);
    }

    const int wave = tid >> 6, lane = tid & 63;
    const int it = wave & 1, jt2 = wave >> 1;
    const int h5 = lane >> 5;
    const int i_loc = it * 32 + (lane & 31);
    const int qtok_i = ktok[i_loc];
    short8 qfh[8], qfl[8];
    {
        size_t qoff = ((size_t)B * T_LEN + qtok_i) * DH + (h5 << 3);
        #pragma unroll
        for (int kt = 0; kt < 8; ++kt) {
            qfh[kt] = *reinterpret_cast<const short8*>(qkh + qoff + kt * 16);
            qfl[kt] = *reinterpret_cast<const short8*>(qkl + qoff + kt * 16);
        }
    }
    __syncthreads();

    const float scale = 0.08838834764831845f;
    float p2[2][16];   // raw masked dots, then P
    #pragma unroll
    for (int jj = 0; jj < 2; ++jj) {
        int jt = jt2 * 2 + jj;
        f32x16 acc = {};
        #pragma unroll
        for (int kt = 0; kt < 8; ++kt) {        // FULL K, 2-term split S
            int so = swz(jt * 32 + (lane & 31), kt * 16 + (h5 << 3));
            short8 afh = *reinterpret_cast<const short8*>(&Kh[so]);
            acc = __builtin_amdgcn_mfma_f32_32x32x16_bf16(afh, qfh[kt], acc, 0, 0, 0);
            acc = __builtin_amdgcn_mfma_f32_32x32x16_bf16(afh, qfl[kt], acc, 0, 0, 0);
        }
        #pragma unroll
        for (int r2 = 0; r2 < 16; ++r2) {
            int jl = (r2 & 3) + ((r2 >> 2) << 3) + (h5 << 2);
            int jf = jt * 32 + jl;
            float s = acc[r2] * (scale * rs_l[jf]);
            p2[jj][r2] = (ktok[jf] == qtok_i) ? -1e5f : s;
        }
    }

    // ---- per-query max over 128 keys ----
    float mloc = p2[0][0];
    #pragma unroll
    for (int jj = 0; jj < 2; ++jj)
        #pragma unroll
        for (int r2 = 0; r2 < 16; ++r2) mloc = fmaxf(mloc, p2[jj][r2]);
    red4b[it][jt2][h5][lane & 31] = mloc;
    __syncthreads();                       // also: all Kh dot-reads done
    if (tid < 64) {
        int it2 = tid >> 5, i = tid & 31;
        mrow[tid] = fmaxf(fmaxf(red4b[it2][0][0][i], red4b[it2][0][1][i]),
                          fmaxf(red4b[it2][1][0][i], red4b[it2][1][1][i]));
    }
    __syncthreads();

    // ---- P = exp(S - m); per-query sum ----
    const float mi = mrow[i_loc];
    float sloc = 0.f;
    #pragma unroll
    for (int jj = 0; jj < 2; ++jj)
        #pragma unroll
        for (int r2 = 0; r2 < 16; ++r2) {
            float p = __expf(p2[jj][r2] - mi);
            p2[jj][r2] = p;
            sloc += p;
        }
    red4b[it][jt2][h5][lane & 31] = sloc;
    __syncthreads();

    // ---- s-merge + global M/S update; write Pb; stage V^T into Kh ----
    if (tid < 64) {
        int it2 = tid >> 5, i = tid & 31;
        float sr = red4b[it2][0][0][i] + red4b[it2][0][1][i] +
                   red4b[it2][1][0][i] + red4b[it2][1][1][i];
        float m = mrow[tid];
        size_t gi = (size_t)B * T_LEN + ktok[tid];
        float aw, bw;
        if (rnd == 0) {
            Mbuf[gi] = m; Sbuf[gi] = sr;
            aw = 0.f; bw = 1.f;
        } else {
            float Mold = Mbuf[gi];
            float Mnew = fmaxf(Mold, m);
            aw = __expf(Mold - Mnew);
            bw = __expf(m - Mnew);
            Sbuf[gi] = Sbuf[gi] * aw + sr * bw;
            Mbuf[gi] = Mnew;
        }
        abrow[tid][0] = aw; abrow[tid][1] = bw;
    }
    // P -> bf16 pairs: quadruple q covers rows 8q+4h5+{0..3} at col i_loc
    #pragma unroll
    for (int jj = 0; jj < 2; ++jj) {
        int jt = jt2 * 2 + jj;
        #pragma unroll
        for (int q = 0; q < 4; ++q) {
            int jhalf = jt * 16 + 4 * q + 2 * h5;   // (row>>1), row even
            unsigned pk0 = cvtpk(p2[jj][4 * q + 0], p2[jj][4 * q + 1]);
            unsigned pk1 = cvtpk(p2[jj][4 * q + 2], p2[jj][4 * q + 3]);
            *reinterpret_cast<unsigned*>(&Pb[jhalf * 128 + i_loc * 2]) = pk0;
            *reinterpret_cast<unsigned*>(&Pb[(jhalf + 1) * 128 + i_loc * 2]) = pk1;
        }
    }
    // restage Kh region as V^T (swizzled rows of V^T: row=d, col=j)
    {
        int j2 = tid >> 1, dbase = (tid & 1) * 64;
        const __hip_bfloat16* vrow = vb + ((size_t)B * T_LEN + ktok[j2]) * DH + dbase;
        #pragma unroll
        for (int mch = 0; mch < 8; ++mch) {
            short8 vv = *reinterpret_cast<const short8*>(vrow + mch * 8);
            #pragma unroll
            for (int e = 0; e < 8; ++e)
                Kh[swz(dbase + mch * 8 + e, j2)] = vv[e];
        }
    }
    __syncthreads();

    // MFMA PV: B-frags read directly from Pb (4 u32 each); A = V^T tiles.
    f32x16 oacc[4] = {};
    #pragma unroll
    for (int jj = 0; jj < 2; ++jj) {
        int jt = jt2 * 2 + jj;
        #pragma unroll
        for (int ks = 0; ks < 2; ++ks) {
            int jb0 = jt * 32 + ks * 16 + h5 * 8;   // even
            union Pack { unsigned u[4]; short8 v; } ph;
            #pragma unroll
            for (int m = 0; m < 4; ++m)
                ph.u[m] = *reinterpret_cast<const unsigned*>(
                    &Pb[((jb0 >> 1) + m) * 128 + i_loc * 2]);
            #pragma unroll
            for (int dt = 0; dt < 4; ++dt) {
                short8 af = *reinterpret_cast<const short8*>(
                    &Kh[swz(dt * 32 + (lane & 31), jb0)]);
                oacc[dt] = __builtin_amdgcn_mfma_f32_32x32x16_bf16(af, ph.v, oacc[dt], 0, 0, 0);
            }
        }
    }
    __syncthreads();   // done reading Pb and V^T(Kh)

    // combine jt2 halves in osc[64][128] f32 (Kh region, XOR-swizzled)
    float* osc = reinterpret_cast<float*>(Kh);
    if (jt2 == 1) {
        #pragma unroll
        for (int dt = 0; dt < 4; ++dt)
            #pragma unroll
            for (int r2 = 0; r2 < 16; ++r2) {
                int d = dt * 32 + (r2 & 3) + ((r2 >> 2) << 3) + (h5 << 2);
                osc[i_loc * 128 + (d ^ (i_loc & 28))] = oacc[dt][r2];
            }
    }
    __syncthreads();
    if (jt2 == 0) {
        #pragma unroll
        for (int dt = 0; dt < 4; ++dt)
            #pragma unroll
            for (int r2 = 0; r2 < 16; ++r2) {
                int d = dt * 32 + (r2 & 3) + ((r2 >> 2) << 3) + (h5 << 2);
                int a = i_loc * 128 + (d ^ (i_loc & 28));
                osc[a] += oacc[dt][r2];
            }
    }
    __syncthreads();

    // online-combined write: rnd 0 stores o_r; rnd>0: attn*a + o_r*b.
    #pragma unroll
    for (int w = 0; w < 8; ++w) {
        int lin = w * 256 + tid;          // float4 index over 64×32
        int rowq = lin >> 5;
        int d0 = (lin & 31) * 4;
        float4 sv4 = *reinterpret_cast<float4*>(&osc[rowq * 128 + (d0 ^ (rowq & 28))]);
        float* gp = attn + ((size_t)B * T_LEN + ktok[rowq]) * DH + d0;
        if (rnd == 0) {
            *reinterpret_cast<float4*>(gp) = sv4;
        } else {
            float aw = abrow[rowq][0], bw = abrow[rowq][1];
            float4 g = *reinterpret_cast<float4*>(gp);
            g.x = g.x * aw + sv4.x * bw;
            g.y = g.y * aw + sv4.y * bw;
            g.z = g.z * aw + sv4.z * bw;
            g.w = g.w * aw + sv4.w * bw;
            *reinterpret_cast<float4*>(gp) = g;
        }
    }
}

// ------------------------------------------------------------------
// K6: out = un-merge-heads(attn / S) @ w_out + b_out, 8 rows/block.
// ------------------------------------------------------------------
__global__ __launch_bounds__(256) void k_out(
    const float* __restrict__ attn, const float* __restrict__ Sbuf,
    const float* __restrict__ wout, const float* __restrict__ bout,
    float* __restrict__ out)
{
    __shared__ float as_[8][EMBD];     // 32 KB
    const int row0 = blockIdx.x * 8;
    const int tid = threadIdx.x;
    #pragma unroll
    for (int rr = 0; rr < 8; ++rr) {
        int row = row0 + rr;
        int b = row >> 12, t = row & 4095;
        for (int u = tid; u < EMBD; u += 256) {
            int h = u >> 7, d = u & 127;
            size_t gi = (size_t)(b * NHEADS + h) * T_LEN + t;
            as_[rr][u] = attn[gi * DH + d] / Sbuf[gi];
        }
    }
    __syncthreads();
    float acc[8][4] = {};
    const float* wp = wout + 4 * tid;
    for (int e = 0; e < EMBD; ++e) {
        float4 w4 = *reinterpret_cast<const float4*>(wp + (size_t)e * EMBD);
        #pragma unroll
        for (int rr = 0; rr < 8; ++rr) {
            float xe = as_[rr][e];
            acc[rr][0] = fmaf(xe, w4.x, acc[rr][0]);
            acc[rr][1] = fmaf(xe, w4.y, acc[rr][1]);
            acc[rr][2] = fmaf(xe, w4.z, acc[rr][2]);
            acc[rr][3] = fmaf(xe, w4.w, acc[rr][3]);
        }
    }
    int j = 4 * tid;
    float b0 = bout[j + 0], b1 = bout[j + 1], b2 = bout[j + 2], b3 = bout[j + 3];
    #pragma unroll
    for (int rr = 0; rr < 8; ++rr) {
        float4 o;
        o.x = acc[rr][0] + b0; o.y = acc[rr][1] + b1;
        o.z = acc[rr][2] + b2; o.w = acc[rr][3] + b3;
        *reinterpret_cast<float4*>(out + (size_t)(row0 + rr) * EMBD + j) = o;
    }
}

// ------------------------------------------------------------------
extern "C" void kernel_launch(void* const* d_in, const int* in_sizes, int n_in,
                              void* d_out, int out_size, void* d_ws, size_t ws_size,
                              hipStream_t stream)
{
    const float* x    = (const float*)d_in[0];
    const float* wqk  = (const float*)d_in[1];
    const float* wv   = (const float*)d_in[2];
    const float* wout = (const float*)d_in[3];
    const float* bout = (const float*)d_in[4];
    const float* rot  = (const float*)d_in[5];
    float* out = (float*)d_out;

    char* ws = (char*)d_ws;
    __hip_bfloat16* qkh       = (__hip_bfloat16*)(ws);              // 16.8 MB
    __hip_bfloat16* qkl       = (__hip_bfloat16*)(ws + 16777216);   // 16.8 MB
    __hip_bfloat16* vb        = (__hip_bfloat16*)(ws + 33554432);   // 16.8 MB
    float*          attn      = (float*)        (ws + 50331648);    // 33.5 MB
    unsigned*       bucketArr = (unsigned*)     (ws + 83886080);    //  2.1 MB
    unsigned*       st        = (unsigned*)     (ws + 85983232);    //  2.1 MB
    float*          Mbuf      = (float*)        (ws + 88080384);
    float*          Sbuf      = (float*)        (ws + 88342528);
    float*          rsn       = (float*)        (ws + 90439680);
    unsigned*       counter   = (unsigned*)     (ws + 90701824);
    unsigned*       flaglist  = (unsigned*)     (ws + 90705920);    // 256 KB

    hipMemsetAsync(counter, 0, 4, stream);
    k_qk_gemm32<<<1024, 256, 0, stream>>>(x, wqk, qkh, qkl, rsn);
    k_hash2f<<<1024, 256, 0, stream>>>(qkh, qkl, rot, bucketArr, counter, flaglist);
    k_fixup<<<256, 128, 0, stream>>>(x, wqk, rot, counter, flaglist, bucketArr);
    k_vproj<<<1024, 256, 0, stream>>>(x, wv, vb);
    k_sort<<<128, 64, 0, stream>>>(bucketArr, st);
    for (int r = 0; r < NHASH; ++r)
        k_bin_pv<<<1024, 256, 0, stream>>>(qkh, qkl, vb, rsn, st, Mbuf, Sbuf, attn, r);
    k_out<<<1024, 256, 0, stream>>>(attn, Sbuf, wout, bout, out);
}

// Round 23
// 949.722 us; speedup vs baseline: 1.4625x; 1.3883x over previous
//
#include <hip/hip_runtime.h>
#include <hip/hip_bf16.h>
#include <math.h>

#define T_LEN 4096
#define EMBD 1024
#define DH 128
#define NHASH 8
#define NHEADS 8
#define FLAG_CAP 65536
#define GAP_THRESH 1e-2f

typedef __attribute__((ext_vector_type(8))) short short8;
typedef __attribute__((ext_vector_type(16))) float f32x16;

// LDS swizzle: row-major [r][128] bf16, 16B-block XOR by (row&7) — G4 fix.
__device__ __forceinline__ int swz(int row, int col) {
    return (row << 7) + (col ^ ((row & 7) << 3));
}
// 64-col bf16 rows variant (128-B rows)
__device__ __forceinline__ int swz64(int row, int col) {
    return row * 64 + (col ^ ((row & 7) << 3));
}
__device__ __forceinline__ unsigned cvtpk(float lo, float hi) {
    unsigned r;
    asm("v_cvt_pk_bf16_f32 %0, %1, %2" : "=v"(r) : "v"(lo), "v"(hi));
    return r;
}
__device__ __forceinline__ float bfu_lo(unsigned u) {
    union { unsigned x; float f; } c; c.x = u << 16; return c.f;
}
__device__ __forceinline__ float bfu_hi(unsigned u) {
    union { unsigned x; float f; } c; c.x = u & 0xffff0000u; return c.f;
}
__device__ __forceinline__ float bfus2f(unsigned short s) {
    union { unsigned x; float f; } c; c.x = ((unsigned)s) << 16; return c.f;
}

// ------------------------------------------------------------------
// P1: x (f32) -> xh + xl (bf16 hi/lo, exact to ~2^-17 rel).
// ------------------------------------------------------------------
__global__ __launch_bounds__(256) void k_prep_x(
    const float* __restrict__ x, __hip_bfloat16* __restrict__ xh,
    __hip_bfloat16* __restrict__ xl)
{
    int gid = blockIdx.x * 256 + threadIdx.x;
    for (int i = gid; i < 2097152; i += 524288) {
        float4 f = reinterpret_cast<const float4*>(x)[i];
        unsigned h01 = cvtpk(f.x, f.y), h23 = cvtpk(f.z, f.w);
        float l0 = f.x - bfu_lo(h01), l1 = f.y - bfu_hi(h01);
        float l2 = f.z - bfu_lo(h23), l3 = f.w - bfu_hi(h23);
        reinterpret_cast<uint2*>(xh)[i] = make_uint2(h01, h23);
        reinterpret_cast<uint2*>(xl)[i] = make_uint2(cvtpk(l0, l1), cvtpk(l2, l3));
    }
}

// ------------------------------------------------------------------
// P2: transpose + split the 3 weight matrices: w[k][n] f32 ->
// wT_h/wT_l[n][k] bf16. Per-mat region: h (1M elems) then l (1M).
// ------------------------------------------------------------------
__global__ __launch_bounds__(256) void k_prep_w(
    const float* __restrict__ w0, const float* __restrict__ w1,
    const float* __restrict__ w2, __hip_bfloat16* __restrict__ wT)
{
    __shared__ float tileT[64 * 65];
    const int mat = blockIdx.x >> 8;
    const int tile = blockIdx.x & 255;
    const int tr = tile >> 4, tc = tile & 15;
    const int k0 = tr * 64, n0c = tc * 64;
    const float* w = (mat == 0) ? w0 : (mat == 1) ? w1 : w2;
    __hip_bfloat16* th = wT + (size_t)mat * 2097152;
    __hip_bfloat16* tl = th + 1048576;
    const int tid = threadIdx.x;

    #pragma unroll
    for (int i = 0; i < 4; ++i) {
        int idx = tid + i * 256;
        int row = idx >> 4, c4 = (idx & 15) * 4;
        float4 f = *reinterpret_cast<const float4*>(
            w + (size_t)(k0 + row) * 1024 + n0c + c4);
        tileT[(c4 + 0) * 65 + row] = f.x;
        tileT[(c4 + 1) * 65 + row] = f.y;
        tileT[(c4 + 2) * 65 + row] = f.z;
        tileT[(c4 + 3) * 65 + row] = f.w;
    }
    __syncthreads();
    #pragma unroll
    for (int i = 0; i < 4; ++i) {
        int idx = tid + i * 256;
        int nl = idx >> 4, kc4 = (idx & 15) * 4;
        float v0 = tileT[nl * 65 + kc4 + 0];
        float v1 = tileT[nl * 65 + kc4 + 1];
        float v2 = tileT[nl * 65 + kc4 + 2];
        float v3 = tileT[nl * 65 + kc4 + 3];
        unsigned h01 = cvtpk(v0, v1), h23 = cvtpk(v2, v3);
        float l0 = v0 - bfu_lo(h01), l1 = v1 - bfu_hi(h01);
        float l2 = v2 - bfu_lo(h23), l3 = v3 - bfu_hi(h23);
        size_t o = (size_t)(n0c + nl) * 1024 + k0 + kc4;
        *reinterpret_cast<uint2*>(th + o) = make_uint2(h01, h23);
        *reinterpret_cast<uint2*>(tl + o) = make_uint2(cvtpk(l0, l1), cvtpk(l2, l3));
    }
}

// ------------------------------------------------------------------
// P3: attn/S (with un-merge-heads gather) -> ah + al (bf16 hi/lo),
// row-major [r = b*4096+t][e = h*128+d].
// ------------------------------------------------------------------
__global__ __launch_bounds__(256) void k_prep_a(
    const float* __restrict__ attn, const float* __restrict__ Sbuf,
    __hip_bfloat16* __restrict__ ah, __hip_bfloat16* __restrict__ al)
{
    int gid = blockIdx.x * 256 + threadIdx.x;
    for (int i = gid; i < 2097152; i += 524288) {
        int r = i >> 8;
        int e4 = (i & 255) * 4;
        int b = r >> 12, t = r & 4095;
        int h = e4 >> 7, d = e4 & 127;
        size_t gi = (size_t)(b * NHEADS + h) * T_LEN + t;
        float4 f = *reinterpret_cast<const float4*>(attn + gi * DH + d);
        float S = Sbuf[gi];
        f.x /= S; f.y /= S; f.z /= S; f.w /= S;
        unsigned h01 = cvtpk(f.x, f.y), h23 = cvtpk(f.z, f.w);
        float l0 = f.x - bfu_lo(h01), l1 = f.y - bfu_hi(h01);
        float l2 = f.z - bfu_lo(h23), l3 = f.w - bfu_hi(h23);
        reinterpret_cast<uint2*>(ah)[i] = make_uint2(h01, h23);
        reinterpret_cast<uint2*>(al)[i] = make_uint2(cvtpk(l0, l1), cvtpk(l2, l3));
    }
}

// ------------------------------------------------------------------
// G: MFMA GEMM, C[8192][1024] = X @ W, split-bf16 3-term
// (wh*xh + wl*xh + wh*xl; dropped xl*wl ~2^-18 rel). Tile 64x128,
// 4 waves (it = m-half, jt2 = n-half), K-step 64 staged in LDS.
// Fragment maps are verbatim clones of the proven k_bin_lse dots.
// EPI: 0 = QK (hi/lo split + rsn), 1 = V (bf16), 2 = OUT (+bias, f32).
// ------------------------------------------------------------------
template <int EPI>
__global__ __launch_bounds__(256, 3) void k_gemm(
    const __hip_bfloat16* __restrict__ Xh_g, const __hip_bfloat16* __restrict__ Xl_g,
    const __hip_bfloat16* __restrict__ Wh_g, const __hip_bfloat16* __restrict__ Wl_g,
    void* __restrict__ o1v, void* __restrict__ o2v,
    float* __restrict__ rsn, const float* __restrict__ bias)
{
    __shared__ char smem[49152];
    short* Wh = (short*)smem;              // [128][64] swz64
    short* Wl = (short*)(smem + 16384);
    short* Xh = (short*)(smem + 32768);    // [64][64] swz64
    short* Xl = (short*)(smem + 40960);

    const int tid = threadIdx.x;
    const int mt = blockIdx.x >> 3;
    const int nt = blockIdx.x & 7;
    const int m0 = mt * 64, n0 = nt * 128;

    const int wave = tid >> 6, lane = tid & 63;
    const int it = wave & 1, jt2 = wave >> 1;
    const int h5 = lane >> 5;
    const int m_loc = it * 32 + (lane & 31);

    f32x16 acc[2] = {};

    for (int ks = 0; ks < 16; ++ks) {
        const int k0 = ks * 64;
        __syncthreads();                   // prior-iter LDS reads done
        for (int u = tid; u < 512; u += 256) {
            int row = u >> 3, blk = u & 7;
            size_t src = (size_t)(m0 + row) * 1024 + k0 + blk * 8;
            int dst = swz64(row, blk * 8);
            *reinterpret_cast<int4*>(&Xh[dst]) = *reinterpret_cast<const int4*>(Xh_g + src);
            *reinterpret_cast<int4*>(&Xl[dst]) = *reinterpret_cast<const int4*>(Xl_g + src);
        }
        for (int u = tid; u < 1024; u += 256) {
            int row = u >> 3, blk = u & 7;
            size_t src = (size_t)(n0 + row) * 1024 + k0 + blk * 8;
            int dst = swz64(row, blk * 8);
            *reinterpret_cast<int4*>(&Wh[dst]) = *reinterpret_cast<const int4*>(Wh_g + src);
            *reinterpret_cast<int4*>(&Wl[dst]) = *reinterpret_cast<const int4*>(Wl_g + src);
        }
        __syncthreads();

        #pragma unroll
        for (int kt = 0; kt < 4; ++kt) {
            int xoff = swz64(m_loc, kt * 16 + h5 * 8);
            short8 xfh = *reinterpret_cast<const short8*>(&Xh[xoff]);
            short8 xfl = *reinterpret_cast<const short8*>(&Xl[xoff]);
            #pragma unroll
            for (int jj = 0; jj < 2; ++jj) {
                int rowN = (jt2 * 2 + jj) * 32 + (lane & 31);
                int woff = swz64(rowN, kt * 16 + h5 * 8);
                short8 wfh = *reinterpret_cast<const short8*>(&Wh[woff]);
                short8 wfl = *reinterpret_cast<const short8*>(&Wl[woff]);
                acc[jj] = __builtin_amdgcn_mfma_f32_32x32x16_bf16(wfh, xfh, acc[jj], 0, 0, 0);
                acc[jj] = __builtin_amdgcn_mfma_f32_32x32x16_bf16(wfl, xfh, acc[jj], 0, 0, 0);
                acc[jj] = __builtin_amdgcn_mfma_f32_32x32x16_bf16(wfh, xfl, acc[jj], 0, 0, 0);
            }
        }
    }
    __syncthreads();

    // C^T -> osc[64 m][128 n] f32, XOR-swizzled (proven osc pattern)
    float* osc = (float*)smem;
    #pragma unroll
    for (int jj = 0; jj < 2; ++jj) {
        int jt = jt2 * 2 + jj;
        #pragma unroll
        for (int r2 = 0; r2 < 16; ++r2) {
            int n = jt * 32 + (r2 & 3) + ((r2 >> 2) << 3) + (h5 << 2);
            osc[m_loc * 128 + (n ^ (m_loc & 28))] = acc[jj][r2];
        }
    }
    __syncthreads();

    // epilogue: 32 lanes per output row (rowm), 4 cols each
    #pragma unroll
    for (int w = 0; w < 8; ++w) {
        int lin = w * 256 + tid;
        int rowm = lin >> 5;
        int c4 = (lin & 31) * 4;
        float4 v4 = *reinterpret_cast<float4*>(&osc[rowm * 128 + (c4 ^ (rowm & 28))]);
        int r = m0 + rowm;
        if constexpr (EPI == 0) {
            float ss = v4.x * v4.x + v4.y * v4.y + v4.z * v4.z + v4.w * v4.w;
            #pragma unroll
            for (int mm = 1; mm < 32; mm <<= 1) ss += __shfl_xor(ss, mm);
            float rs = 1.0f / sqrtf(fmaxf(ss, 1e-12f));
            int b = r >> 12, t = r & 4095;
            int h = n0 >> 7;                      // tile spans exactly one head
            size_t base = ((size_t)(b * NHEADS + h) * T_LEN + t) * DH + c4;
            unsigned h01 = cvtpk(v4.x, v4.y), h23 = cvtpk(v4.z, v4.w);
            float l0 = v4.x - bfu_lo(h01), l1 = v4.y - bfu_hi(h01);
            float l2 = v4.z - bfu_lo(h23), l3 = v4.w - bfu_hi(h23);
            *reinterpret_cast<uint2*>((__hip_bfloat16*)o1v + base) = make_uint2(h01, h23);
            *reinterpret_cast<uint2*>((__hip_bfloat16*)o2v + base) =
                make_uint2(cvtpk(l0, l1), cvtpk(l2, l3));
            if ((lin & 31) == 0)
                rsn[(size_t)(b * NHEADS + h) * T_LEN + t] = rs;
        } else if constexpr (EPI == 1) {
            int b = r >> 12, t = r & 4095;
            int n = n0 + c4;
            int h = n >> 7, d = n & 127;
            size_t base = ((size_t)(b * NHEADS + h) * T_LEN + t) * DH + d;
            *reinterpret_cast<uint2*>((__hip_bfloat16*)o1v + base) =
                make_uint2(cvtpk(v4.x, v4.y), cvtpk(v4.z, v4.w));
        } else {
            int n = n0 + c4;
            float4 o;
            o.x = v4.x + bias[n + 0]; o.y = v4.y + bias[n + 1];
            o.z = v4.z + bias[n + 2]; o.w = v4.w + bias[n + 3];
            *reinterpret_cast<float4*>((float*)o1v + (size_t)r * 1024 + n) = o;
        }
    }
}

// ------------------------------------------------------------------
// K1b: LSH hash, ALL F32 with top-2 gap test (proven round 20/22).
// ------------------------------------------------------------------
__global__ __launch_bounds__(256) void k_hash2f(
    const __hip_bfloat16* __restrict__ qkh, const __hip_bfloat16* __restrict__ qkl,
    const float* __restrict__ rot, unsigned* __restrict__ bucketArr,
    unsigned* __restrict__ counter, unsigned* __restrict__ flaglist)
{
    __shared__ float qs[8][EMBD];      // 32 KB
    const int tok0 = blockIdx.x * 8;
    const int tid = threadIdx.x;
    const int j = 4 * tid;
    const int h = j >> 7, d = j & 127;

    #pragma unroll
    for (int tk = 0; tk < 8; ++tk) {
        int row = tok0 + tk;
        int b = row >> 12, t = row & 4095;
        size_t base = ((size_t)(b * NHEADS + h) * T_LEN + t) * DH + d;
        ushort4 h4 = *reinterpret_cast<const ushort4*>(qkh + base);
        ushort4 l4 = *reinterpret_cast<const ushort4*>(qkl + base);
        qs[tk][j + 0] = bfus2f(h4.x) + bfus2f(l4.x);
        qs[tk][j + 1] = bfus2f(h4.y) + bfus2f(l4.y);
        qs[tk][j + 2] = bfus2f(h4.z) + bfus2f(l4.z);
        qs[tk][j + 3] = bfus2f(h4.w) + bfus2f(l4.w);
    }
    __syncthreads();

    const int r = tid >> 5, i = tid & 31;
    const float* rp = rot + r * 32 + i;
    for (int hh = 0; hh < NHEADS; ++hh) {
        float acc[8] = {};
        for (int f = 0; f < DH; ++f) {
            float rv = rp[(size_t)f * 256];
            #pragma unroll
            for (int tk = 0; tk < 8; ++tk)
                acc[tk] = fmaf(qs[tk][hh * DH + f], rv, acc[tk]);
        }
        #pragma unroll
        for (int tk = 0; tk < 8; ++tk) {
            float v, v2; int idx;
            float a = acc[tk];
            if (a >= 0.0f) { v = a; idx = i; v2 = -a; }
            else           { v = -a; idx = i + 32; v2 = a; }
            #pragma unroll
            for (int m = 1; m < 32; m <<= 1) {
                float ov = __shfl_xor(v, m);
                int oi = __shfl_xor(idx, m);
                float ov2 = __shfl_xor(v2, m);
                bool owin = (ov > v) || (ov == v && oi < idx);
                float lv1 = owin ? v : ov;
                float wv2 = owin ? ov2 : v2;
                if (owin) { v = ov; idx = oi; }
                v2 = fmaxf(lv1, wv2);
            }
            if (i == 0) {
                int row = tok0 + tk;
                int b = row >> 12, t = row & 4095;
                int B = b * NHEADS + hh;
                bucketArr[((size_t)B * NHASH + r) * T_LEN + t] = (unsigned)idx;
                if (v - v2 < GAP_THRESH) {
                    unsigned p = atomicAdd(counter, 1u);
                    if (p < FLAG_CAP)
                        flaglist[p] = ((unsigned)B << 15) | ((unsigned)r << 12) | (unsigned)t;
                }
            }
        }
    }
}

// ------------------------------------------------------------------
// K1c: exact f64 fixup for flagged near-tie argmaxes (proven).
// ------------------------------------------------------------------
__global__ __launch_bounds__(128) void k_fixup(
    const float* __restrict__ x, const float* __restrict__ wqk,
    const float* __restrict__ rot, const unsigned* __restrict__ counter,
    const unsigned* __restrict__ flaglist, unsigned* __restrict__ bucketArr)
{
    __shared__ float xsf[EMBD];
    __shared__ double qk64[DH];
    __shared__ double vals[64];
    unsigned n = *counter;
    if (n > FLAG_CAP) n = FLAG_CAP;
    for (unsigned item = blockIdx.x; item < n; item += gridDim.x) {
        unsigned pk = flaglist[item];
        int t = pk & 4095, r = (pk >> 12) & 7, B = pk >> 15;
        int b = B >> 3, h = B & 7;
        for (int u = threadIdx.x; u < 256; u += 128)
            reinterpret_cast<float4*>(xsf)[u] =
                reinterpret_cast<const float4*>(x + (size_t)(b * T_LEN + t) * EMBD)[u];
        __syncthreads();
        {
            double a = 0.0;
            const float* wp = wqk + h * DH + threadIdx.x;
            for (int e = 0; e < EMBD; ++e)
                a = fma((double)xsf[e], (double)wp[(size_t)e * EMBD], a);
            qk64[threadIdx.x] = a;
        }
        __syncthreads();
        if (threadIdx.x < 32) {
            const float* rp = rot + r * 32 + threadIdx.x;
            double acc2 = 0.0;
            for (int f = 0; f < DH; ++f)
                acc2 = fma(qk64[f], (double)rp[(size_t)f * 256], acc2);
            vals[threadIdx.x] = acc2;
            vals[threadIdx.x + 32] = -acc2;
        }
        __syncthreads();
        if (threadIdx.x == 0) {
            double best = vals[0]; int bi = 0;
            for (int u = 1; u < 64; ++u)
                if (vals[u] > best) { best = vals[u]; bi = u; }
            bucketArr[((size_t)B * NHASH + r) * T_LEN + t] = (unsigned)bi;
        }
        __syncthreads();
    }
}

// ------------------------------------------------------------------
// K3: stable counting sort per (B, hash-round) — unchanged (proven).
// ------------------------------------------------------------------
__global__ __launch_bounds__(64) void k_sort(
    const unsigned* __restrict__ bucketArr, unsigned* __restrict__ st)
{
    __shared__ unsigned short bkt[T_LEN];
    __shared__ unsigned hist[64][64];
    __shared__ unsigned bstart[64];
    const int B = blockIdx.x >> 3, r = blockIdx.x & 7;
    const unsigned* src = bucketArr + ((size_t)B * NHASH + r) * T_LEN;
    const int tid = threadIdx.x;

    for (int k = tid; k < T_LEN; k += 64) bkt[k] = (unsigned short)src[k];
    for (int k = tid; k < 64 * 64; k += 64) (&hist[0][0])[k] = 0;
    __syncthreads();
    {
        const int base = tid * 64;
        for (int k = 0; k < 64; ++k) hist[tid][bkt[base + k]]++;
    }
    __syncthreads();
    {
        unsigned tot = 0;
        for (int c = 0; c < 64; ++c) tot += hist[c][tid];
        bstart[tid] = tot;
    }
    __syncthreads();
    if (tid == 0) {
        unsigned run = 0;
        for (int q = 0; q < 64; ++q) { unsigned c = bstart[q]; bstart[q] = run; run += c; }
    }
    __syncthreads();
    {
        unsigned run = bstart[tid];
        for (int c = 0; c < 64; ++c) { unsigned h = hist[c][tid]; hist[c][tid] = run; run += h; }
    }
    __syncthreads();
    {
        unsigned* dst = st + ((size_t)B * NHASH + r) * T_LEN;
        const int base = tid * 64;
        for (int k = 0; k < 64; ++k) {
            unsigned bb2 = bkt[base + k];
            unsigned p = hist[tid][bb2]++;
            dst[p] = (unsigned)(base + k);
        }
    }
}

// ------------------------------------------------------------------
// K4: per-bin attention, ONE PASS per hash round — unchanged (proven).
// ------------------------------------------------------------------
__global__ __launch_bounds__(256, 3) void k_bin_pv(
    const __hip_bfloat16* __restrict__ qkh, const __hip_bfloat16* __restrict__ qkl,
    const __hip_bfloat16* __restrict__ vb, const float* __restrict__ rsn,
    const unsigned* __restrict__ st, float* __restrict__ Mbuf,
    float* __restrict__ Sbuf, float* __restrict__ attn, int rnd)
{
    __shared__ short Kh[128 * 128];        // K_hi -> V^T -> osc f32[64][128]
    __shared__ unsigned short Pb[64 * 128];// P bf16: [(j>>1)][i][j&1], 16 KB
    __shared__ int ktok[128];
    __shared__ float rs_l[128];
    __shared__ float red4b[2][2][2][32];   // [it][jt2][h5][col]
    __shared__ float mrow[64];
    __shared__ float abrow[64][2];         // per-query (a, b) weights

    const int tid = threadIdx.x;
    const int c = blockIdx.x & 63;
    const int B = blockIdx.x >> 6;
    const unsigned* stp = st + ((size_t)B * NHASH + rnd) * T_LEN;

    if (tid < 128) {
        int cc = (tid < 64) ? c : (c == 0 ? 1 : c - 1);
        int tok = (int)stp[cc * 64 + (tid & 63)];
        ktok[tid] = tok;
        rs_l[tid] = rsn[(size_t)B * T_LEN + tok];
    }
    __syncthreads();

    // stage K_hi (swizzled)
    for (int u = tid; u < 128 * 16; u += 256) {
        int row = u >> 4, blk = u & 15;
        *reinterpret_cast<int4*>(&Kh[swz(row, blk * 8)]) =
            *reinterpret_cast<const int4*>(qkh + ((size_t)B * T_LEN + ktok[row]) * DH + blk * 8);
    }

    const int wave = tid >> 6, lane = tid & 63;
    const int it = wave & 1, jt2 = wave >> 1;
    const int h5 = lane >> 5;
    const int i_loc = it * 32 + (lane & 31);
    const int qtok_i = ktok[i_loc];
    short8 qfh[8], qfl[8];
    {
        size_t qoff = ((size_t)B * T_LEN + qtok_i) * DH + (h5 << 3);
        #pragma unroll
        for (int kt = 0; kt < 8; ++kt) {
            qfh[kt] = *reinterpret_cast<const short8*>(qkh + qoff + kt * 16);
            qfl[kt] = *reinterpret_cast<const short8*>(qkl + qoff + kt * 16);
        }
    }
    __syncthreads();

    const float scale = 0.08838834764831845f;
    float p2[2][16];   // raw masked dots, then P
    #pragma unroll
    for (int jj = 0; jj < 2; ++jj) {
        int jt = jt2 * 2 + jj;
        f32x16 acc = {};
        #pragma unroll
        for (int kt = 0; kt < 8; ++kt) {        // FULL K, 2-term split S
            int so = swz(jt * 32 + (lane & 31), kt * 16 + (h5 << 3));
            short8 afh = *reinterpret_cast<const short8*>(&Kh[so]);
            acc = __builtin_amdgcn_mfma_f32_32x32x16_bf16(afh, qfh[kt], acc, 0, 0, 0);
            acc = __builtin_amdgcn_mfma_f32_32x32x16_bf16(afh, qfl[kt], acc, 0, 0, 0);
        }
        #pragma unroll
        for (int r2 = 0; r2 < 16; ++r2) {
            int jl = (r2 & 3) + ((r2 >> 2) << 3) + (h5 << 2);
            int jf = jt * 32 + jl;
            float s = acc[r2] * (scale * rs_l[jf]);
            p2[jj][r2] = (ktok[jf] == qtok_i) ? -1e5f : s;
        }
    }

    // ---- per-query max over 128 keys ----
    float mloc = p2[0][0];
    #pragma unroll
    for (int jj = 0; jj < 2; ++jj)
        #pragma unroll
        for (int r2 = 0; r2 < 16; ++r2) mloc = fmaxf(mloc, p2[jj][r2]);
    red4b[it][jt2][h5][lane & 31] = mloc;
    __syncthreads();                       // also: all Kh dot-reads done
    if (tid < 64) {
        int it2 = tid >> 5, i = tid & 31;
        mrow[tid] = fmaxf(fmaxf(red4b[it2][0][0][i], red4b[it2][0][1][i]),
                          fmaxf(red4b[it2][1][0][i], red4b[it2][1][1][i]));
    }
    __syncthreads();

    // ---- P = exp(S - m); per-query sum ----
    const float mi = mrow[i_loc];
    float sloc = 0.f;
    #pragma unroll
    for (int jj = 0; jj < 2; ++jj)
        #pragma unroll
        for (int r2 = 0; r2 < 16; ++r2) {
            float p = __expf(p2[jj][r2] - mi);
            p2[jj][r2] = p;
            sloc += p;
        }
    red4b[it][jt2][h5][lane & 31] = sloc;
    __syncthreads();

    // ---- s-merge + global M/S update; write Pb; stage V^T into Kh ----
    if (tid < 64) {
        int it2 = tid >> 5, i = tid & 31;
        float sr = red4b[it2][0][0][i] + red4b[it2][0][1][i] +
                   red4b[it2][1][0][i] + red4b[it2][1][1][i];
        float m = mrow[tid];
        size_t gi = (size_t)B * T_LEN + ktok[tid];
        float aw, bw;
        if (rnd == 0) {
            Mbuf[gi] = m; Sbuf[gi] = sr;
            aw = 0.f; bw = 1.f;
        } else {
            float Mold = Mbuf[gi];
            float Mnew = fmaxf(Mold, m);
            aw = __expf(Mold - Mnew);
            bw = __expf(m - Mnew);
            Sbuf[gi] = Sbuf[gi] * aw + sr * bw;
            Mbuf[gi] = Mnew;
        }
        abrow[tid][0] = aw; abrow[tid][1] = bw;
    }
    // P -> bf16 pairs: quadruple q covers rows 8q+4h5+{0..3} at col i_loc
    #pragma unroll
    for (int jj = 0; jj < 2; ++jj) {
        int jt = jt2 * 2 + jj;
        #pragma unroll
        for (int q = 0; q < 4; ++q) {
            int jhalf = jt * 16 + 4 * q + 2 * h5;   // (row>>1), row even
            unsigned pk0 = cvtpk(p2[jj][4 * q + 0], p2[jj][4 * q + 1]);
            unsigned pk1 = cvtpk(p2[jj][4 * q + 2], p2[jj][4 * q + 3]);
            *reinterpret_cast<unsigned*>(&Pb[jhalf * 128 + i_loc * 2]) = pk0;
            *reinterpret_cast<unsigned*>(&Pb[(jhalf + 1) * 128 + i_loc * 2]) = pk1;
        }
    }
    // restage Kh region as V^T (swizzled rows of V^T: row=d, col=j)
    {
        int j2 = tid >> 1, dbase = (tid & 1) * 64;
        const __hip_bfloat16* vrow = vb + ((size_t)B * T_LEN + ktok[j2]) * DH + dbase;
        #pragma unroll
        for (int mch = 0; mch < 8; ++mch) {
            short8 vv = *reinterpret_cast<const short8*>(vrow + mch * 8);
            #pragma unroll
            for (int e = 0; e < 8; ++e)
                Kh[swz(dbase + mch * 8 + e, j2)] = vv[e];
        }
    }
    __syncthreads();

    // MFMA PV: B-frags read directly from Pb (4 u32 each); A = V^T tiles.
    f32x16 oacc[4] = {};
    #pragma unroll
    for (int jj = 0; jj < 2; ++jj) {
        int jt = jt2 * 2 + jj;
        #pragma unroll
        for (int ks = 0; ks < 2; ++ks) {
            int jb0 = jt * 32 + ks * 16 + h5 * 8;   // even
            union Pack { unsigned u[4]; short8 v; } ph;
            #pragma unroll
            for (int m = 0; m < 4; ++m)
                ph.u[m] = *reinterpret_cast<const unsigned*>(
                    &Pb[((jb0 >> 1) + m) * 128 + i_loc * 2]);
            #pragma unroll
            for (int dt = 0; dt < 4; ++dt) {
                short8 af = *reinterpret_cast<const short8*>(
                    &Kh[swz(dt * 32 + (lane & 31), jb0)]);
                oacc[dt] = __builtin_amdgcn_mfma_f32_32x32x16_bf16(af, ph.v, oacc[dt], 0, 0, 0);
            }
        }
    }
    __syncthreads();   // done reading Pb and V^T(Kh)

    // combine jt2 halves in osc[64][128] f32 (Kh region, XOR-swizzled)
    float* osc = reinterpret_cast<float*>(Kh);
    if (jt2 == 1) {
        #pragma unroll
        for (int dt = 0; dt < 4; ++dt)
            #pragma unroll
            for (int r2 = 0; r2 < 16; ++r2) {
                int d = dt * 32 + (r2 & 3) + ((r2 >> 2) << 3) + (h5 << 2);
                osc[i_loc * 128 + (d ^ (i_loc & 28))] = oacc[dt][r2];
            }
    }
    __syncthreads();
    if (jt2 == 0) {
        #pragma unroll
        for (int dt = 0; dt < 4; ++dt)
            #pragma unroll
            for (int r2 = 0; r2 < 16; ++r2) {
                int d = dt * 32 + (r2 & 3) + ((r2 >> 2) << 3) + (h5 << 2);
                int a = i_loc * 128 + (d ^ (i_loc & 28));
                osc[a] += oacc[dt][r2];
            }
    }
    __syncthreads();

    // online-combined write: rnd 0 stores o_r; rnd>0: attn*a + o_r*b.
    #pragma unroll
    for (int w = 0; w < 8; ++w) {
        int lin = w * 256 + tid;          // float4 index over 64×32
        int rowq = lin >> 5;
        int d0 = (lin & 31) * 4;
        float4 sv4 = *reinterpret_cast<float4*>(&osc[rowq * 128 + (d0 ^ (rowq & 28))]);
        float* gp = attn + ((size_t)B * T_LEN + ktok[rowq]) * DH + d0;
        if (rnd == 0) {
            *reinterpret_cast<float4*>(gp) = sv4;
        } else {
            float aw = abrow[rowq][0], bw = abrow[rowq][1];
            float4 g = *reinterpret_cast<float4*>(gp);
            g.x = g.x * aw + sv4.x * bw;
            g.y = g.y * aw + sv4.y * bw;
            g.z = g.z * aw + sv4.z * bw;
            g.w = g.w * aw + sv4.w * bw;
            *reinterpret_cast<float4*>(gp) = g;
        }
    }
}

// ------------------------------------------------------------------
extern "C" void kernel_launch(void* const* d_in, const int* in_sizes, int n_in,
                              void* d_out, int out_size, void* d_ws, size_t ws_size,
                              hipStream_t stream)
{
    const float* x    = (const float*)d_in[0];
    const float* wqk  = (const float*)d_in[1];
    const float* wv   = (const float*)d_in[2];
    const float* wout = (const float*)d_in[3];
    const float* bout = (const float*)d_in[4];
    const float* rot  = (const float*)d_in[5];
    float* out = (float*)d_out;

    // ws layout (~103.6 MB; round-0 proved ws >= 107 MB):
    //  [0, 16.8M)      qkh   -> later ah
    //  [16.8M, 33.6M)  qkl   -> later al
    //  [33.6M, 50.3M)  vb
    //  [50.3M, 83.9M)  attn f32; FIRST aliased as xh (16.8) + xl (16.8)
    //  [83.9M..]       bucketArr, st, Mbuf, Sbuf, rsn, counter, flaglist
    //  [90.97M, 103.6M) wT: qk_h, qk_l, v_h, v_l, out_h, out_l (2MB each)
    char* ws = (char*)d_ws;
    __hip_bfloat16* qkh       = (__hip_bfloat16*)(ws);
    __hip_bfloat16* qkl       = (__hip_bfloat16*)(ws + 16777216);
    __hip_bfloat16* vb        = (__hip_bfloat16*)(ws + 33554432);
    float*          attn      = (float*)        (ws + 50331648);
    __hip_bfloat16* xh        = (__hip_bfloat16*)(ws + 50331648);
    __hip_bfloat16* xl        = (__hip_bfloat16*)(ws + 67108864);
    unsigned*       bucketArr = (unsigned*)     (ws + 83886080);
    unsigned*       st        = (unsigned*)     (ws + 85983232);
    float*          Mbuf      = (float*)        (ws + 88080384);
    float*          Sbuf      = (float*)        (ws + 88342528);
    float*          rsn       = (float*)        (ws + 90439680);
    unsigned*       counter   = (unsigned*)     (ws + 90701824);
    unsigned*       flaglist  = (unsigned*)     (ws + 90705920);
    __hip_bfloat16* wT        = (__hip_bfloat16*)(ws + 90968064);
    __hip_bfloat16* ah        = qkh;   // alias, used after pv
    __hip_bfloat16* al        = qkl;

    hipMemsetAsync(counter, 0, 4, stream);
    k_prep_x<<<2048, 256, 0, stream>>>(x, xh, xl);
    k_prep_w<<<768, 256, 0, stream>>>(wqk, wv, wout, wT);
    k_gemm<0><<<1024, 256, 0, stream>>>(xh, xl, wT, wT + 1048576,
                                        qkh, qkl, rsn, nullptr);
    k_gemm<1><<<1024, 256, 0, stream>>>(xh, xl, wT + 2097152, wT + 3145728,
                                        vb, nullptr, nullptr, nullptr);
    k_hash2f<<<1024, 256, 0, stream>>>(qkh, qkl, rot, bucketArr, counter, flaglist);
    k_fixup<<<256, 128, 0, stream>>>(x, wqk, rot, counter, flaglist, bucketArr);
    k_sort<<<128, 64, 0, stream>>>(bucketArr, st);
    for (int r = 0; r < NHASH; ++r)
        k_bin_pv<<<1024, 256, 0, stream>>>(qkh, qkl, vb, rsn, st, Mbuf, Sbuf, attn, r);
    k_prep_a<<<2048, 256, 0, stream>>>(attn, Sbuf, ah, al);
    k_gemm<2><<<1024, 256, 0, stream>>>(ah, al, wT + 4194304, wT + 5242880,
                                        out, nullptr, nullptr, bout);
}

// Round 24
// 810.619 us; speedup vs baseline: 1.7135x; 1.1716x over previous
//
#include <hip/hip_runtime.h>
#include <hip/hip_bf16.h>
#include <math.h>

#define T_LEN 4096
#define EMBD 1024
#define DH 128
#define NHASH 8
#define NHEADS 8
#define FLAG_CAP 65536
#define GAP_THRESH 2e-3f

typedef __attribute__((ext_vector_type(8))) short short8;
typedef __attribute__((ext_vector_type(16))) float f32x16;

// LDS swizzle: row-major [r][128] bf16, 16B-block XOR by (row&7) — G4 fix.
__device__ __forceinline__ int swz(int row, int col) {
    return (row << 7) + (col ^ ((row & 7) << 3));
}
// 64-col bf16 rows variant (128-B rows)
__device__ __forceinline__ int swz64(int row, int col) {
    return row * 64 + (col ^ ((row & 7) << 3));
}
__device__ __forceinline__ unsigned cvtpk(float lo, float hi) {
    unsigned r;
    asm("v_cvt_pk_bf16_f32 %0, %1, %2" : "=v"(r) : "v"(lo), "v"(hi));
    return r;
}
__device__ __forceinline__ float bfu_lo(unsigned u) {
    union { unsigned x; float f; } c; c.x = u << 16; return c.f;
}
__device__ __forceinline__ float bfu_hi(unsigned u) {
    union { unsigned x; float f; } c; c.x = u & 0xffff0000u; return c.f;
}
__device__ __forceinline__ float bfus2f(unsigned short s) {
    union { unsigned x; float f; } c; c.x = ((unsigned)s) << 16; return c.f;
}

// ------------------------------------------------------------------
// P1: x (f32) -> xh + xl (bf16 hi/lo, exact to ~2^-17 rel).
// ------------------------------------------------------------------
__global__ __launch_bounds__(256) void k_prep_x(
    const float* __restrict__ x, __hip_bfloat16* __restrict__ xh,
    __hip_bfloat16* __restrict__ xl)
{
    int gid = blockIdx.x * 256 + threadIdx.x;
    for (int i = gid; i < 2097152; i += 524288) {
        float4 f = reinterpret_cast<const float4*>(x)[i];
        unsigned h01 = cvtpk(f.x, f.y), h23 = cvtpk(f.z, f.w);
        float l0 = f.x - bfu_lo(h01), l1 = f.y - bfu_hi(h01);
        float l2 = f.z - bfu_lo(h23), l3 = f.w - bfu_hi(h23);
        reinterpret_cast<uint2*>(xh)[i] = make_uint2(h01, h23);
        reinterpret_cast<uint2*>(xl)[i] = make_uint2(cvtpk(l0, l1), cvtpk(l2, l3));
    }
}

// ------------------------------------------------------------------
// P2: transpose + split the 3 weight matrices: w[k][n] f32 ->
// wT_h/wT_l[n][k] bf16. Per-mat region: h (1M elems) then l (1M).
// ------------------------------------------------------------------
__global__ __launch_bounds__(256) void k_prep_w(
    const float* __restrict__ w0, const float* __restrict__ w1,
    const float* __restrict__ w2, __hip_bfloat16* __restrict__ wT)
{
    __shared__ float tileT[64 * 65];
    const int mat = blockIdx.x >> 8;
    const int tile = blockIdx.x & 255;
    const int tr = tile >> 4, tc = tile & 15;
    const int k0 = tr * 64, n0c = tc * 64;
    const float* w = (mat == 0) ? w0 : (mat == 1) ? w1 : w2;
    __hip_bfloat16* th = wT + (size_t)mat * 2097152;
    __hip_bfloat16* tl = th + 1048576;
    const int tid = threadIdx.x;

    #pragma unroll
    for (int i = 0; i < 4; ++i) {
        int idx = tid + i * 256;
        int row = idx >> 4, c4 = (idx & 15) * 4;
        float4 f = *reinterpret_cast<const float4*>(
            w + (size_t)(k0 + row) * 1024 + n0c + c4);
        tileT[(c4 + 0) * 65 + row] = f.x;
        tileT[(c4 + 1) * 65 + row] = f.y;
        tileT[(c4 + 2) * 65 + row] = f.z;
        tileT[(c4 + 3) * 65 + row] = f.w;
    }
    __syncthreads();
    #pragma unroll
    for (int i = 0; i < 4; ++i) {
        int idx = tid + i * 256;
        int nl = idx >> 4, kc4 = (idx & 15) * 4;
        float v0 = tileT[nl * 65 + kc4 + 0];
        float v1 = tileT[nl * 65 + kc4 + 1];
        float v2 = tileT[nl * 65 + kc4 + 2];
        float v3 = tileT[nl * 65 + kc4 + 3];
        unsigned h01 = cvtpk(v0, v1), h23 = cvtpk(v2, v3);
        float l0 = v0 - bfu_lo(h01), l1 = v1 - bfu_hi(h01);
        float l2 = v2 - bfu_lo(h23), l3 = v3 - bfu_hi(h23);
        size_t o = (size_t)(n0c + nl) * 1024 + k0 + kc4;
        *reinterpret_cast<uint2*>(th + o) = make_uint2(h01, h23);
        *reinterpret_cast<uint2*>(tl + o) = make_uint2(cvtpk(l0, l1), cvtpk(l2, l3));
    }
}

// ------------------------------------------------------------------
// P3: attn/S (with un-merge-heads gather) -> ah + al (bf16 hi/lo),
// row-major [r = b*4096+t][e = h*128+d].
// ------------------------------------------------------------------
__global__ __launch_bounds__(256) void k_prep_a(
    const float* __restrict__ attn, const float* __restrict__ Sbuf,
    __hip_bfloat16* __restrict__ ah, __hip_bfloat16* __restrict__ al)
{
    int gid = blockIdx.x * 256 + threadIdx.x;
    for (int i = gid; i < 2097152; i += 524288) {
        int r = i >> 8;
        int e4 = (i & 255) * 4;
        int b = r >> 12, t = r & 4095;
        int h = e4 >> 7, d = e4 & 127;
        size_t gi = (size_t)(b * NHEADS + h) * T_LEN + t;
        float4 f = *reinterpret_cast<const float4*>(attn + gi * DH + d);
        float S = Sbuf[gi];
        f.x /= S; f.y /= S; f.z /= S; f.w /= S;
        unsigned h01 = cvtpk(f.x, f.y), h23 = cvtpk(f.z, f.w);
        float l0 = f.x - bfu_lo(h01), l1 = f.y - bfu_hi(h01);
        float l2 = f.z - bfu_lo(h23), l3 = f.w - bfu_hi(h23);
        reinterpret_cast<uint2*>(ah)[i] = make_uint2(h01, h23);
        reinterpret_cast<uint2*>(al)[i] = make_uint2(cvtpk(l0, l1), cvtpk(l2, l3));
    }
}

// ------------------------------------------------------------------
// G: MFMA GEMM, C[8192][1024] = X @ W, split-bf16 3-term — proven r23.
// EPI: 0 = QK (hi/lo split + rsn), 1 = V (bf16), 2 = OUT (+bias, f32).
// ------------------------------------------------------------------
template <int EPI>
__global__ __launch_bounds__(256, 3) void k_gemm(
    const __hip_bfloat16* __restrict__ Xh_g, const __hip_bfloat16* __restrict__ Xl_g,
    const __hip_bfloat16* __restrict__ Wh_g, const __hip_bfloat16* __restrict__ Wl_g,
    void* __restrict__ o1v, void* __restrict__ o2v,
    float* __restrict__ rsn, const float* __restrict__ bias)
{
    __shared__ char smem[49152];
    short* Wh = (short*)smem;              // [128][64] swz64
    short* Wl = (short*)(smem + 16384);
    short* Xh = (short*)(smem + 32768);    // [64][64] swz64
    short* Xl = (short*)(smem + 40960);

    const int tid = threadIdx.x;
    const int mt = blockIdx.x >> 3;
    const int nt = blockIdx.x & 7;
    const int m0 = mt * 64, n0 = nt * 128;

    const int wave = tid >> 6, lane = tid & 63;
    const int it = wave & 1, jt2 = wave >> 1;
    const int h5 = lane >> 5;
    const int m_loc = it * 32 + (lane & 31);

    f32x16 acc[2] = {};

    for (int ks = 0; ks < 16; ++ks) {
        const int k0 = ks * 64;
        __syncthreads();                   // prior-iter LDS reads done
        for (int u = tid; u < 512; u += 256) {
            int row = u >> 3, blk = u & 7;
            size_t src = (size_t)(m0 + row) * 1024 + k0 + blk * 8;
            int dst = swz64(row, blk * 8);
            *reinterpret_cast<int4*>(&Xh[dst]) = *reinterpret_cast<const int4*>(Xh_g + src);
            *reinterpret_cast<int4*>(&Xl[dst]) = *reinterpret_cast<const int4*>(Xl_g + src);
        }
        for (int u = tid; u < 1024; u += 256) {
            int row = u >> 3, blk = u & 7;
            size_t src = (size_t)(n0 + row) * 1024 + k0 + blk * 8;
            int dst = swz64(row, blk * 8);
            *reinterpret_cast<int4*>(&Wh[dst]) = *reinterpret_cast<const int4*>(Wh_g + src);
            *reinterpret_cast<int4*>(&Wl[dst]) = *reinterpret_cast<const int4*>(Wl_g + src);
        }
        __syncthreads();

        #pragma unroll
        for (int kt = 0; kt < 4; ++kt) {
            int xoff = swz64(m_loc, kt * 16 + h5 * 8);
            short8 xfh = *reinterpret_cast<const short8*>(&Xh[xoff]);
            short8 xfl = *reinterpret_cast<const short8*>(&Xl[xoff]);
            #pragma unroll
            for (int jj = 0; jj < 2; ++jj) {
                int rowN = (jt2 * 2 + jj) * 32 + (lane & 31);
                int woff = swz64(rowN, kt * 16 + h5 * 8);
                short8 wfh = *reinterpret_cast<const short8*>(&Wh[woff]);
                short8 wfl = *reinterpret_cast<const short8*>(&Wl[woff]);
                acc[jj] = __builtin_amdgcn_mfma_f32_32x32x16_bf16(wfh, xfh, acc[jj], 0, 0, 0);
                acc[jj] = __builtin_amdgcn_mfma_f32_32x32x16_bf16(wfl, xfh, acc[jj], 0, 0, 0);
                acc[jj] = __builtin_amdgcn_mfma_f32_32x32x16_bf16(wfh, xfl, acc[jj], 0, 0, 0);
            }
        }
    }
    __syncthreads();

    // C^T -> osc[64 m][128 n] f32, XOR-swizzled (proven osc pattern)
    float* osc = (float*)smem;
    #pragma unroll
    for (int jj = 0; jj < 2; ++jj) {
        int jt = jt2 * 2 + jj;
        #pragma unroll
        for (int r2 = 0; r2 < 16; ++r2) {
            int n = jt * 32 + (r2 & 3) + ((r2 >> 2) << 3) + (h5 << 2);
            osc[m_loc * 128 + (n ^ (m_loc & 28))] = acc[jj][r2];
        }
    }
    __syncthreads();

    // epilogue: 32 lanes per output row (rowm), 4 cols each
    #pragma unroll
    for (int w = 0; w < 8; ++w) {
        int lin = w * 256 + tid;
        int rowm = lin >> 5;
        int c4 = (lin & 31) * 4;
        float4 v4 = *reinterpret_cast<float4*>(&osc[rowm * 128 + (c4 ^ (rowm & 28))]);
        int r = m0 + rowm;
        if constexpr (EPI == 0) {
            float ss = v4.x * v4.x + v4.y * v4.y + v4.z * v4.z + v4.w * v4.w;
            #pragma unroll
            for (int mm = 1; mm < 32; mm <<= 1) ss += __shfl_xor(ss, mm);
            float rs = 1.0f / sqrtf(fmaxf(ss, 1e-12f));
            int b = r >> 12, t = r & 4095;
            int h = n0 >> 7;                      // tile spans exactly one head
            size_t base = ((size_t)(b * NHEADS + h) * T_LEN + t) * DH + c4;
            unsigned h01 = cvtpk(v4.x, v4.y), h23 = cvtpk(v4.z, v4.w);
            float l0 = v4.x - bfu_lo(h01), l1 = v4.y - bfu_hi(h01);
            float l2 = v4.z - bfu_lo(h23), l3 = v4.w - bfu_hi(h23);
            *reinterpret_cast<uint2*>((__hip_bfloat16*)o1v + base) = make_uint2(h01, h23);
            *reinterpret_cast<uint2*>((__hip_bfloat16*)o2v + base) =
                make_uint2(cvtpk(l0, l1), cvtpk(l2, l3));
            if ((lin & 31) == 0)
                rsn[(size_t)(b * NHEADS + h) * T_LEN + t] = rs;
        } else if constexpr (EPI == 1) {
            int b = r >> 12, t = r & 4095;
            int n = n0 + c4;
            int h = n >> 7, d = n & 127;
            size_t base = ((size_t)(b * NHEADS + h) * T_LEN + t) * DH + d;
            *reinterpret_cast<uint2*>((__hip_bfloat16*)o1v + base) =
                make_uint2(cvtpk(v4.x, v4.y), cvtpk(v4.z, v4.w));
        } else {
            int n = n0 + c4;
            float4 o;
            o.x = v4.x + bias[n + 0]; o.y = v4.y + bias[n + 1];
            o.z = v4.z + bias[n + 2]; o.w = v4.w + bias[n + 3];
            *reinterpret_cast<float4*>((float*)o1v + (size_t)r * 1024 + n) = o;
        }
    }
}

// ------------------------------------------------------------------
// K1b: LSH hash, ALL F32 with top-2 gap test (proven round 20/22).
// ------------------------------------------------------------------
__global__ __launch_bounds__(256) void k_hash2f(
    const __hip_bfloat16* __restrict__ qkh, const __hip_bfloat16* __restrict__ qkl,
    const float* __restrict__ rot, unsigned* __restrict__ bucketArr,
    unsigned* __restrict__ counter, unsigned* __restrict__ flaglist)
{
    __shared__ float qs[8][EMBD];      // 32 KB
    const int tok0 = blockIdx.x * 8;
    const int tid = threadIdx.x;
    const int j = 4 * tid;
    const int h = j >> 7, d = j & 127;

    #pragma unroll
    for (int tk = 0; tk < 8; ++tk) {
        int row = tok0 + tk;
        int b = row >> 12, t = row & 4095;
        size_t base = ((size_t)(b * NHEADS + h) * T_LEN + t) * DH + d;
        ushort4 h4 = *reinterpret_cast<const ushort4*>(qkh + base);
        ushort4 l4 = *reinterpret_cast<const ushort4*>(qkl + base);
        qs[tk][j + 0] = bfus2f(h4.x) + bfus2f(l4.x);
        qs[tk][j + 1] = bfus2f(h4.y) + bfus2f(l4.y);
        qs[tk][j + 2] = bfus2f(h4.z) + bfus2f(l4.z);
        qs[tk][j + 3] = bfus2f(h4.w) + bfus2f(l4.w);
    }
    __syncthreads();

    const int r = tid >> 5, i = tid & 31;
    const float* rp = rot + r * 32 + i;
    for (int hh = 0; hh < NHEADS; ++hh) {
        float acc[8] = {};
        for (int f = 0; f < DH; ++f) {
            float rv = rp[(size_t)f * 256];
            #pragma unroll
            for (int tk = 0; tk < 8; ++tk)
                acc[tk] = fmaf(qs[tk][hh * DH + f], rv, acc[tk]);
        }
        #pragma unroll
        for (int tk = 0; tk < 8; ++tk) {
            float v, v2; int idx;
            float a = acc[tk];
            if (a >= 0.0f) { v = a; idx = i; v2 = -a; }
            else           { v = -a; idx = i + 32; v2 = a; }
            #pragma unroll
            for (int m = 1; m < 32; m <<= 1) {
                float ov = __shfl_xor(v, m);
                int oi = __shfl_xor(idx, m);
                float ov2 = __shfl_xor(v2, m);
                bool owin = (ov > v) || (ov == v && oi < idx);
                float lv1 = owin ? v : ov;
                float wv2 = owin ? ov2 : v2;
                if (owin) { v = ov; idx = oi; }
                v2 = fmaxf(lv1, wv2);
            }
            if (i == 0) {
                int row = tok0 + tk;
                int b = row >> 12, t = row & 4095;
                int B = b * NHEADS + hh;
                bucketArr[((size_t)B * NHASH + r) * T_LEN + t] = (unsigned)idx;
                if (v - v2 < GAP_THRESH) {
                    unsigned p = atomicAdd(counter, 1u);
                    if (p < FLAG_CAP)
                        flaglist[p] = ((unsigned)B << 15) | ((unsigned)r << 12) | (unsigned)t;
                }
            }
        }
    }
}

// ------------------------------------------------------------------
// K1c: exact f64 fixup for flagged near-tie argmaxes. 256 threads,
// e-SPLIT qk row (2x shorter f64 chain; f64 combine ~1e-16 dev);
// grid 1024 (>= 1 block per item in the common case).
// ------------------------------------------------------------------
__global__ __launch_bounds__(256) void k_fixup(
    const float* __restrict__ x, const float* __restrict__ wqk,
    const float* __restrict__ rot, const unsigned* __restrict__ counter,
    const unsigned* __restrict__ flaglist, unsigned* __restrict__ bucketArr)
{
    __shared__ float xsf[EMBD];
    __shared__ double qk64p[2][DH];
    __shared__ double vals[64];
    unsigned n = *counter;
    if (n > FLAG_CAP) n = FLAG_CAP;
    for (unsigned item = blockIdx.x; item < n; item += gridDim.x) {
        unsigned pk = flaglist[item];
        int t = pk & 4095, r = (pk >> 12) & 7, B = pk >> 15;
        int b = B >> 3, h = B & 7;
        reinterpret_cast<float4*>(xsf)[threadIdx.x] =
            reinterpret_cast<const float4*>(x + (size_t)(b * T_LEN + t) * EMBD)[threadIdx.x];
        __syncthreads();
        {
            int d = threadIdx.x & 127, gh = threadIdx.x >> 7;
            double a = 0.0;
            const float* wp = wqk + h * DH + d;
            const int e0 = gh << 9;
            for (int e = e0; e < e0 + 512; ++e)
                a = fma((double)xsf[e], (double)wp[(size_t)e * EMBD], a);
            qk64p[gh][d] = a;
        }
        __syncthreads();
        if (threadIdx.x < 32) {
            const float* rp = rot + r * 32 + threadIdx.x;
            double acc2 = 0.0;
            for (int f = 0; f < DH; ++f)
                acc2 = fma(qk64p[0][f] + qk64p[1][f], (double)rp[(size_t)f * 256], acc2);
            vals[threadIdx.x] = acc2;
            vals[threadIdx.x + 32] = -acc2;
        }
        __syncthreads();
        if (threadIdx.x == 0) {
            double best = vals[0]; int bi = 0;
            for (int u = 1; u < 64; ++u)
                if (vals[u] > best) { best = vals[u]; bi = u; }
            bucketArr[((size_t)B * NHASH + r) * T_LEN + t] = (unsigned)bi;
        }
        __syncthreads();
    }
}

// ------------------------------------------------------------------
// K3: stable counting sort per (B, hash-round) — unchanged (proven).
// ------------------------------------------------------------------
__global__ __launch_bounds__(64) void k_sort(
    const unsigned* __restrict__ bucketArr, unsigned* __restrict__ st)
{
    __shared__ unsigned short bkt[T_LEN];
    __shared__ unsigned hist[64][64];
    __shared__ unsigned bstart[64];
    const int B = blockIdx.x >> 3, r = blockIdx.x & 7;
    const unsigned* src = bucketArr + ((size_t)B * NHASH + r) * T_LEN;
    const int tid = threadIdx.x;

    for (int k = tid; k < T_LEN; k += 64) bkt[k] = (unsigned short)src[k];
    for (int k = tid; k < 64 * 64; k += 64) (&hist[0][0])[k] = 0;
    __syncthreads();
    {
        const int base = tid * 64;
        for (int k = 0; k < 64; ++k) hist[tid][bkt[base + k]]++;
    }
    __syncthreads();
    {
        unsigned tot = 0;
        for (int c = 0; c < 64; ++c) tot += hist[c][tid];
        bstart[tid] = tot;
    }
    __syncthreads();
    if (tid == 0) {
        unsigned run = 0;
        for (int q = 0; q < 64; ++q) { unsigned c = bstart[q]; bstart[q] = run; run += c; }
    }
    __syncthreads();
    {
        unsigned run = bstart[tid];
        for (int c = 0; c < 64; ++c) { unsigned h = hist[c][tid]; hist[c][tid] = run; run += h; }
    }
    __syncthreads();
    {
        unsigned* dst = st + ((size_t)B * NHASH + r) * T_LEN;
        const int base = tid * 64;
        for (int k = 0; k < 64; ++k) {
            unsigned bb2 = bkt[base + k];
            unsigned p = hist[tid][bb2]++;
            dst[p] = (unsigned)(base + k);
        }
    }
}

// ------------------------------------------------------------------
// K4: per-bin attention, ONE PASS per hash round — unchanged (proven).
// ------------------------------------------------------------------
__global__ __launch_bounds__(256, 3) void k_bin_pv(
    const __hip_bfloat16* __restrict__ qkh, const __hip_bfloat16* __restrict__ qkl,
    const __hip_bfloat16* __restrict__ vb, const float* __restrict__ rsn,
    const unsigned* __restrict__ st, float* __restrict__ Mbuf,
    float* __restrict__ Sbuf, float* __restrict__ attn, int rnd)
{
    __shared__ short Kh[128 * 128];        // K_hi -> V^T -> osc f32[64][128]
    __shared__ unsigned short Pb[64 * 128];// P bf16: [(j>>1)][i][j&1], 16 KB
    __shared__ int ktok[128];
    __shared__ float rs_l[128];
    __shared__ float red4b[2][2][2][32];   // [it][jt2][h5][col]
    __shared__ float mrow[64];
    __shared__ float abrow[64][2];         // per-query (a, b) weights

    const int tid = threadIdx.x;
    const int c = blockIdx.x & 63;
    const int B = blockIdx.x >> 6;
    const unsigned* stp = st + ((size_t)B * NHASH + rnd) * T_LEN;

    if (tid < 128) {
        int cc = (tid < 64) ? c : (c == 0 ? 1 : c - 1);
        int tok = (int)stp[cc * 64 + (tid & 63)];
        ktok[tid] = tok;
        rs_l[tid] = rsn[(size_t)B * T_LEN + tok];
    }
    __syncthreads();

    // stage K_hi (swizzled)
    for (int u = tid; u < 128 * 16; u += 256) {
        int row = u >> 4, blk = u & 15;
        *reinterpret_cast<int4*>(&Kh[swz(row, blk * 8)]) =
            *reinterpret_cast<const int4*>(qkh + ((size_t)B * T_LEN + ktok[row]) * DH + blk * 8);
    }

    const int wave = tid >> 6, lane = tid & 63;
    const int it = wave & 1, jt2 = wave >> 1;
    const int h5 = lane >> 5;
    const int i_loc = it * 32 + (lane & 31);
    const int qtok_i = ktok[i_loc];
    short8 qfh[8], qfl[8];
    {
        size_t qoff = ((size_t)B * T_LEN + qtok_i) * DH + (h5 << 3);
        #pragma unroll
        for (int kt = 0; kt < 8; ++kt) {
            qfh[kt] = *reinterpret_cast<const short8*>(qkh + qoff + kt * 16);
            qfl[kt] = *reinterpret_cast<const short8*>(qkl + qoff + kt * 16);
        }
    }
    __syncthreads();

    const float scale = 0.08838834764831845f;
    float p2[2][16];   // raw masked dots, then P
    #pragma unroll
    for (int jj = 0; jj < 2; ++jj) {
        int jt = jt2 * 2 + jj;
        f32x16 acc = {};
        #pragma unroll
        for (int kt = 0; kt < 8; ++kt) {        // FULL K, 2-term split S
            int so = swz(jt * 32 + (lane & 31), kt * 16 + (h5 << 3));
            short8 afh = *reinterpret_cast<const short8*>(&Kh[so]);
            acc = __builtin_amdgcn_mfma_f32_32x32x16_bf16(afh, qfh[kt], acc, 0, 0, 0);
            acc = __builtin_amdgcn_mfma_f32_32x32x16_bf16(afh, qfl[kt], acc, 0, 0, 0);
        }
        #pragma unroll
        for (int r2 = 0; r2 < 16; ++r2) {
            int jl = (r2 & 3) + ((r2 >> 2) << 3) + (h5 << 2);
            int jf = jt * 32 + jl;
            float s = acc[r2] * (scale * rs_l[jf]);
            p2[jj][r2] = (ktok[jf] == qtok_i) ? -1e5f : s;
        }
    }

    // ---- per-query max over 128 keys ----
    float mloc = p2[0][0];
    #pragma unroll
    for (int jj = 0; jj < 2; ++jj)
        #pragma unroll
        for (int r2 = 0; r2 < 16; ++r2) mloc = fmaxf(mloc, p2[jj][r2]);
    red4b[it][jt2][h5][lane & 31] = mloc;
    __syncthreads();                       // also: all Kh dot-reads done
    if (tid < 64) {
        int it2 = tid >> 5, i = tid & 31;
        mrow[tid] = fmaxf(fmaxf(red4b[it2][0][0][i], red4b[it2][0][1][i]),
                          fmaxf(red4b[it2][1][0][i], red4b[it2][1][1][i]));
    }
    __syncthreads();

    // ---- P = exp(S - m); per-query sum ----
    const float mi = mrow[i_loc];
    float sloc = 0.f;
    #pragma unroll
    for (int jj = 0; jj < 2; ++jj)
        #pragma unroll
        for (int r2 = 0; r2 < 16; ++r2) {
            float p = __expf(p2[jj][r2] - mi);
            p2[jj][r2] = p;
            sloc += p;
        }
    red4b[it][jt2][h5][lane & 31] = sloc;
    __syncthreads();

    // ---- s-merge + global M/S update; write Pb; stage V^T into Kh ----
    if (tid < 64) {
        int it2 = tid >> 5, i = tid & 31;
        float sr = red4b[it2][0][0][i] + red4b[it2][0][1][i] +
                   red4b[it2][1][0][i] + red4b[it2][1][1][i];
        float m = mrow[tid];
        size_t gi = (size_t)B * T_LEN + ktok[tid];
        float aw, bw;
        if (rnd == 0) {
            Mbuf[gi] = m; Sbuf[gi] = sr;
            aw = 0.f; bw = 1.f;
        } else {
            float Mold = Mbuf[gi];
            float Mnew = fmaxf(Mold, m);
            aw = __expf(Mold - Mnew);
            bw = __expf(m - Mnew);
            Sbuf[gi] = Sbuf[gi] * aw + sr * bw;
            Mbuf[gi] = Mnew;
        }
        abrow[tid][0] = aw; abrow[tid][1] = bw;
    }
    // P -> bf16 pairs: quadruple q covers rows 8q+4h5+{0..3} at col i_loc
    #pragma unroll
    for (int jj = 0; jj < 2; ++jj) {
        int jt = jt2 * 2 + jj;
        #pragma unroll
        for (int q = 0; q < 4; ++q) {
            int jhalf = jt * 16 + 4 * q + 2 * h5;   // (row>>1), row even
            unsigned pk0 = cvtpk(p2[jj][4 * q + 0], p2[jj][4 * q + 1]);
            unsigned pk1 = cvtpk(p2[jj][4 * q + 2], p2[jj][4 * q + 3]);
            *reinterpret_cast<unsigned*>(&Pb[jhalf * 128 + i_loc * 2]) = pk0;
            *reinterpret_cast<unsigned*>(&Pb[(jhalf + 1) * 128 + i_loc * 2]) = pk1;
        }
    }
    // restage Kh region as V^T (swizzled rows of V^T: row=d, col=j)
    {
        int j2 = tid >> 1, dbase = (tid & 1) * 64;
        const __hip_bfloat16* vrow = vb + ((size_t)B * T_LEN + ktok[j2]) * DH + dbase;
        #pragma unroll
        for (int mch = 0; mch < 8; ++mch) {
            short8 vv = *reinterpret_cast<const short8*>(vrow + mch * 8);
            #pragma unroll
            for (int e = 0; e < 8; ++e)
                Kh[swz(dbase + mch * 8 + e, j2)] = vv[e];
        }
    }
    __syncthreads();

    // MFMA PV: B-frags read directly from Pb (4 u32 each); A = V^T tiles.
    f32x16 oacc[4] = {};
    #pragma unroll
    for (int jj = 0; jj < 2; ++jj) {
        int jt = jt2 * 2 + jj;
        #pragma unroll
        for (int ks = 0; ks < 2; ++ks) {
            int jb0 = jt * 32 + ks * 16 + h5 * 8;   // even
            union Pack { unsigned u[4]; short8 v; } ph;
            #pragma unroll
            for (int m = 0; m < 4; ++m)
                ph.u[m] = *reinterpret_cast<const unsigned*>(
                    &Pb[((jb0 >> 1) + m) * 128 + i_loc * 2]);
            #pragma unroll
            for (int dt = 0; dt < 4; ++dt) {
                short8 af = *reinterpret_cast<const short8*>(
                    &Kh[swz(dt * 32 + (lane & 31), jb0)]);
                oacc[dt] = __builtin_amdgcn_mfma_f32_32x32x16_bf16(af, ph.v, oacc[dt], 0, 0, 0);
            }
        }
    }
    __syncthreads();   // done reading Pb and V^T(Kh)

    // combine jt2 halves in osc[64][128] f32 (Kh region, XOR-swizzled)
    float* osc = reinterpret_cast<float*>(Kh);
    if (jt2 == 1) {
        #pragma unroll
        for (int dt = 0; dt < 4; ++dt)
            #pragma unroll
            for (int r2 = 0; r2 < 16; ++r2) {
                int d = dt * 32 + (r2 & 3) + ((r2 >> 2) << 3) + (h5 << 2);
                osc[i_loc * 128 + (d ^ (i_loc & 28))] = oacc[dt][r2];
            }
    }
    __syncthreads();
    if (jt2 == 0) {
        #pragma unroll
        for (int dt = 0; dt < 4; ++dt)
            #pragma unroll
            for (int r2 = 0; r2 < 16; ++r2) {
                int d = dt * 32 + (r2 & 3) + ((r2 >> 2) << 3) + (h5 << 2);
                int a = i_loc * 128 + (d ^ (i_loc & 28));
                osc[a] += oacc[dt][r2];
            }
    }
    __syncthreads();

    // online-combined write: rnd 0 stores o_r; rnd>0: attn*a + o_r*b.
    #pragma unroll
    for (int w = 0; w < 8; ++w) {
        int lin = w * 256 + tid;          // float4 index over 64×32
        int rowq = lin >> 5;
        int d0 = (lin & 31) * 4;
        float4 sv4 = *reinterpret_cast<float4*>(&osc[rowq * 128 + (d0 ^ (rowq & 28))]);
        float* gp = attn + ((size_t)B * T_LEN + ktok[rowq]) * DH + d0;
        if (rnd == 0) {
            *reinterpret_cast<float4*>(gp) = sv4;
        } else {
            float aw = abrow[rowq][0], bw = abrow[rowq][1];
            float4 g = *reinterpret_cast<float4*>(gp);
            g.x = g.x * aw + sv4.x * bw;
            g.y = g.y * aw + sv4.y * bw;
            g.z = g.z * aw + sv4.z * bw;
            g.w = g.w * aw + sv4.w * bw;
            *reinterpret_cast<float4*>(gp) = g;
        }
    }
}

// ------------------------------------------------------------------
extern "C" void kernel_launch(void* const* d_in, const int* in_sizes, int n_in,
                              void* d_out, int out_size, void* d_ws, size_t ws_size,
                              hipStream_t stream)
{
    const float* x    = (const float*)d_in[0];
    const float* wqk  = (const float*)d_in[1];
    const float* wv   = (const float*)d_in[2];
    const float* wout = (const float*)d_in[3];
    const float* bout = (const float*)d_in[4];
    const float* rot  = (const float*)d_in[5];
    float* out = (float*)d_out;

    // ws layout (~103.6 MB; round-0 proved ws >= 107 MB):
    char* ws = (char*)d_ws;
    __hip_bfloat16* qkh       = (__hip_bfloat16*)(ws);
    __hip_bfloat16* qkl       = (__hip_bfloat16*)(ws + 16777216);
    __hip_bfloat16* vb        = (__hip_bfloat16*)(ws + 33554432);
    float*          attn      = (float*)        (ws + 50331648);
    __hip_bfloat16* xh        = (__hip_bfloat16*)(ws + 50331648);
    __hip_bfloat16* xl        = (__hip_bfloat16*)(ws + 67108864);
    unsigned*       bucketArr = (unsigned*)     (ws + 83886080);
    unsigned*       st        = (unsigned*)     (ws + 85983232);
    float*          Mbuf      = (float*)        (ws + 88080384);
    float*          Sbuf      = (float*)        (ws + 88342528);
    float*          rsn       = (float*)        (ws + 90439680);
    unsigned*       counter   = (unsigned*)     (ws + 90701824);
    unsigned*       flaglist  = (unsigned*)     (ws + 90705920);
    __hip_bfloat16* wT        = (__hip_bfloat16*)(ws + 90968064);
    __hip_bfloat16* ah        = qkh;   // alias, used after pv
    __hip_bfloat16* al        = qkl;

    hipMemsetAsync(counter, 0, 4, stream);
    k_prep_x<<<2048, 256, 0, stream>>>(x, xh, xl);
    k_prep_w<<<768, 256, 0, stream>>>(wqk, wv, wout, wT);
    k_gemm<0><<<1024, 256, 0, stream>>>(xh, xl, wT, wT + 1048576,
                                        qkh, qkl, rsn, nullptr);
    k_gemm<1><<<1024, 256, 0, stream>>>(xh, xl, wT + 2097152, wT + 3145728,
                                        vb, nullptr, nullptr, nullptr);
    k_hash2f<<<1024, 256, 0, stream>>>(qkh, qkl, rot, bucketArr, counter, flaglist);
    k_fixup<<<1024, 256, 0, stream>>>(x, wqk, rot, counter, flaglist, bucketArr);
    k_sort<<<128, 64, 0, stream>>>(bucketArr, st);
    for (int r = 0; r < NHASH; ++r)
        k_bin_pv<<<1024, 256, 0, stream>>>(qkh, qkl, vb, rsn, st, Mbuf, Sbuf, attn, r);
    k_prep_a<<<2048, 256, 0, stream>>>(attn, Sbuf, ah, al);
    k_gemm<2><<<1024, 256, 0, stream>>>(ah, al, wT + 4194304, wT + 5242880,
                                        out, nullptr, nullptr, bout);
}

// Round 25
// 726.558 us; speedup vs baseline: 1.9118x; 1.1157x over previous
//
#include <hip/hip_runtime.h>
#include <hip/hip_bf16.h>
#include <math.h>

#define T_LEN 4096
#define EMBD 1024
#define DH 128
#define NHASH 8
#define NHEADS 8
#define FLAG_CAP 65536
#define GAP_THRESH 2e-3f

typedef __attribute__((ext_vector_type(8))) short short8;
typedef __attribute__((ext_vector_type(16))) float f32x16;

// LDS swizzle: row-major [r][128] bf16, 16B-block XOR by (row&7) — G4 fix.
__device__ __forceinline__ int swz(int row, int col) {
    return (row << 7) + (col ^ ((row & 7) << 3));
}
// 64-col bf16 rows variant (128-B rows)
__device__ __forceinline__ int swz64(int row, int col) {
    return row * 64 + (col ^ ((row & 7) << 3));
}
__device__ __forceinline__ unsigned cvtpk(float lo, float hi) {
    unsigned r;
    asm("v_cvt_pk_bf16_f32 %0, %1, %2" : "=v"(r) : "v"(lo), "v"(hi));
    return r;
}
__device__ __forceinline__ float bfu_lo(unsigned u) {
    union { unsigned x; float f; } c; c.x = u << 16; return c.f;
}
__device__ __forceinline__ float bfu_hi(unsigned u) {
    union { unsigned x; float f; } c; c.x = u & 0xffff0000u; return c.f;
}
__device__ __forceinline__ float bfus2f(unsigned short s) {
    union { unsigned x; float f; } c; c.x = ((unsigned)s) << 16; return c.f;
}

// ------------------------------------------------------------------
// P1: x (f32) -> xh + xl (bf16 hi/lo, exact to ~2^-17 rel).
// ------------------------------------------------------------------
__global__ __launch_bounds__(256) void k_prep_x(
    const float* __restrict__ x, __hip_bfloat16* __restrict__ xh,
    __hip_bfloat16* __restrict__ xl)
{
    int gid = blockIdx.x * 256 + threadIdx.x;
    for (int i = gid; i < 2097152; i += 524288) {
        float4 f = reinterpret_cast<const float4*>(x)[i];
        unsigned h01 = cvtpk(f.x, f.y), h23 = cvtpk(f.z, f.w);
        float l0 = f.x - bfu_lo(h01), l1 = f.y - bfu_hi(h01);
        float l2 = f.z - bfu_lo(h23), l3 = f.w - bfu_hi(h23);
        reinterpret_cast<uint2*>(xh)[i] = make_uint2(h01, h23);
        reinterpret_cast<uint2*>(xl)[i] = make_uint2(cvtpk(l0, l1), cvtpk(l2, l3));
    }
}

// ------------------------------------------------------------------
// P2: transpose + split the 3 weight matrices: w[k][n] f32 ->
// wT_h/wT_l[n][k] bf16. Per-mat region: h (1M elems) then l (1M).
// ------------------------------------------------------------------
__global__ __launch_bounds__(256) void k_prep_w(
    const float* __restrict__ w0, const float* __restrict__ w1,
    const float* __restrict__ w2, __hip_bfloat16* __restrict__ wT)
{
    __shared__ float tileT[64 * 65];
    const int mat = blockIdx.x >> 8;
    const int tile = blockIdx.x & 255;
    const int tr = tile >> 4, tc = tile & 15;
    const int k0 = tr * 64, n0c = tc * 64;
    const float* w = (mat == 0) ? w0 : (mat == 1) ? w1 : w2;
    __hip_bfloat16* th = wT + (size_t)mat * 2097152;
    __hip_bfloat16* tl = th + 1048576;
    const int tid = threadIdx.x;

    #pragma unroll
    for (int i = 0; i < 4; ++i) {
        int idx = tid + i * 256;
        int row = idx >> 4, c4 = (idx & 15) * 4;
        float4 f = *reinterpret_cast<const float4*>(
            w + (size_t)(k0 + row) * 1024 + n0c + c4);
        tileT[(c4 + 0) * 65 + row] = f.x;
        tileT[(c4 + 1) * 65 + row] = f.y;
        tileT[(c4 + 2) * 65 + row] = f.z;
        tileT[(c4 + 3) * 65 + row] = f.w;
    }
    __syncthreads();
    #pragma unroll
    for (int i = 0; i < 4; ++i) {
        int idx = tid + i * 256;
        int nl = idx >> 4, kc4 = (idx & 15) * 4;
        float v0 = tileT[nl * 65 + kc4 + 0];
        float v1 = tileT[nl * 65 + kc4 + 1];
        float v2 = tileT[nl * 65 + kc4 + 2];
        float v3 = tileT[nl * 65 + kc4 + 3];
        unsigned h01 = cvtpk(v0, v1), h23 = cvtpk(v2, v3);
        float l0 = v0 - bfu_lo(h01), l1 = v1 - bfu_hi(h01);
        float l2 = v2 - bfu_lo(h23), l3 = v3 - bfu_hi(h23);
        size_t o = (size_t)(n0c + nl) * 1024 + k0 + kc4;
        *reinterpret_cast<uint2*>(th + o) = make_uint2(h01, h23);
        *reinterpret_cast<uint2*>(tl + o) = make_uint2(cvtpk(l0, l1), cvtpk(l2, l3));
    }
}

// ------------------------------------------------------------------
// P4: rot [f=128][r=8][i=32] f32 -> rotT_h/rotT_l [ri=256][f=128] bf16.
// ------------------------------------------------------------------
__global__ __launch_bounds__(256) void k_prep_rot(
    const float* __restrict__ rot, __hip_bfloat16* __restrict__ rth,
    __hip_bfloat16* __restrict__ rtl)
{
    int gid = blockIdx.x * 256 + threadIdx.x;   // 8192 float4-chunks
    int ri = gid >> 5, f0 = (gid & 31) * 4;
    float v0 = rot[(size_t)(f0 + 0) * 256 + ri];
    float v1 = rot[(size_t)(f0 + 1) * 256 + ri];
    float v2 = rot[(size_t)(f0 + 2) * 256 + ri];
    float v3 = rot[(size_t)(f0 + 3) * 256 + ri];
    unsigned h01 = cvtpk(v0, v1), h23 = cvtpk(v2, v3);
    float l0 = v0 - bfu_lo(h01), l1 = v1 - bfu_hi(h01);
    float l2 = v2 - bfu_lo(h23), l3 = v3 - bfu_hi(h23);
    size_t o = (size_t)ri * 128 + f0;
    *reinterpret_cast<uint2*>(rth + o) = make_uint2(h01, h23);
    *reinterpret_cast<uint2*>(rtl + o) = make_uint2(cvtpk(l0, l1), cvtpk(l2, l3));
}

// ------------------------------------------------------------------
// P3: attn/S (with un-merge-heads gather) -> ah + al (bf16 hi/lo).
// ------------------------------------------------------------------
__global__ __launch_bounds__(256) void k_prep_a(
    const float* __restrict__ attn, const float* __restrict__ Sbuf,
    __hip_bfloat16* __restrict__ ah, __hip_bfloat16* __restrict__ al)
{
    int gid = blockIdx.x * 256 + threadIdx.x;
    for (int i = gid; i < 2097152; i += 524288) {
        int r = i >> 8;
        int e4 = (i & 255) * 4;
        int b = r >> 12, t = r & 4095;
        int h = e4 >> 7, d = e4 & 127;
        size_t gi = (size_t)(b * NHEADS + h) * T_LEN + t;
        float4 f = *reinterpret_cast<const float4*>(attn + gi * DH + d);
        float S = Sbuf[gi];
        f.x /= S; f.y /= S; f.z /= S; f.w /= S;
        unsigned h01 = cvtpk(f.x, f.y), h23 = cvtpk(f.z, f.w);
        float l0 = f.x - bfu_lo(h01), l1 = f.y - bfu_hi(h01);
        float l2 = f.z - bfu_lo(h23), l3 = f.w - bfu_hi(h23);
        reinterpret_cast<uint2*>(ah)[i] = make_uint2(h01, h23);
        reinterpret_cast<uint2*>(al)[i] = make_uint2(cvtpk(l0, l1), cvtpk(l2, l3));
    }
}

// ------------------------------------------------------------------
// G: MFMA GEMM, C[8192][1024] = X @ W, split-bf16 3-term — proven r23.
// EPI: 0 = QK (hi/lo split + rsn), 1 = V (bf16), 2 = OUT (+bias, f32).
// ------------------------------------------------------------------
template <int EPI>
__global__ __launch_bounds__(256, 3) void k_gemm(
    const __hip_bfloat16* __restrict__ Xh_g, const __hip_bfloat16* __restrict__ Xl_g,
    const __hip_bfloat16* __restrict__ Wh_g, const __hip_bfloat16* __restrict__ Wl_g,
    void* __restrict__ o1v, void* __restrict__ o2v,
    float* __restrict__ rsn, const float* __restrict__ bias)
{
    __shared__ char smem[49152];
    short* Wh = (short*)smem;              // [128][64] swz64
    short* Wl = (short*)(smem + 16384);
    short* Xh = (short*)(smem + 32768);    // [64][64] swz64
    short* Xl = (short*)(smem + 40960);

    const int tid = threadIdx.x;
    const int mt = blockIdx.x >> 3;
    const int nt = blockIdx.x & 7;
    const int m0 = mt * 64, n0 = nt * 128;

    const int wave = tid >> 6, lane = tid & 63;
    const int it = wave & 1, jt2 = wave >> 1;
    const int h5 = lane >> 5;
    const int m_loc = it * 32 + (lane & 31);

    f32x16 acc[2] = {};

    for (int ks = 0; ks < 16; ++ks) {
        const int k0 = ks * 64;
        __syncthreads();                   // prior-iter LDS reads done
        for (int u = tid; u < 512; u += 256) {
            int row = u >> 3, blk = u & 7;
            size_t src = (size_t)(m0 + row) * 1024 + k0 + blk * 8;
            int dst = swz64(row, blk * 8);
            *reinterpret_cast<int4*>(&Xh[dst]) = *reinterpret_cast<const int4*>(Xh_g + src);
            *reinterpret_cast<int4*>(&Xl[dst]) = *reinterpret_cast<const int4*>(Xl_g + src);
        }
        for (int u = tid; u < 1024; u += 256) {
            int row = u >> 3, blk = u & 7;
            size_t src = (size_t)(n0 + row) * 1024 + k0 + blk * 8;
            int dst = swz64(row, blk * 8);
            *reinterpret_cast<int4*>(&Wh[dst]) = *reinterpret_cast<const int4*>(Wh_g + src);
            *reinterpret_cast<int4*>(&Wl[dst]) = *reinterpret_cast<const int4*>(Wl_g + src);
        }
        __syncthreads();

        #pragma unroll
        for (int kt = 0; kt < 4; ++kt) {
            int xoff = swz64(m_loc, kt * 16 + h5 * 8);
            short8 xfh = *reinterpret_cast<const short8*>(&Xh[xoff]);
            short8 xfl = *reinterpret_cast<const short8*>(&Xl[xoff]);
            #pragma unroll
            for (int jj = 0; jj < 2; ++jj) {
                int rowN = (jt2 * 2 + jj) * 32 + (lane & 31);
                int woff = swz64(rowN, kt * 16 + h5 * 8);
                short8 wfh = *reinterpret_cast<const short8*>(&Wh[woff]);
                short8 wfl = *reinterpret_cast<const short8*>(&Wl[woff]);
                acc[jj] = __builtin_amdgcn_mfma_f32_32x32x16_bf16(wfh, xfh, acc[jj], 0, 0, 0);
                acc[jj] = __builtin_amdgcn_mfma_f32_32x32x16_bf16(wfl, xfh, acc[jj], 0, 0, 0);
                acc[jj] = __builtin_amdgcn_mfma_f32_32x32x16_bf16(wfh, xfl, acc[jj], 0, 0, 0);
            }
        }
    }
    __syncthreads();

    // C^T -> osc[64 m][128 n] f32, XOR-swizzled (proven osc pattern)
    float* osc = (float*)smem;
    #pragma unroll
    for (int jj = 0; jj < 2; ++jj) {
        int jt = jt2 * 2 + jj;
        #pragma unroll
        for (int r2 = 0; r2 < 16; ++r2) {
            int n = jt * 32 + (r2 & 3) + ((r2 >> 2) << 3) + (h5 << 2);
            osc[m_loc * 128 + (n ^ (m_loc & 28))] = acc[jj][r2];
        }
    }
    __syncthreads();

    // epilogue: 32 lanes per output row (rowm), 4 cols each
    #pragma unroll
    for (int w = 0; w < 8; ++w) {
        int lin = w * 256 + tid;
        int rowm = lin >> 5;
        int c4 = (lin & 31) * 4;
        float4 v4 = *reinterpret_cast<float4*>(&osc[rowm * 128 + (c4 ^ (rowm & 28))]);
        int r = m0 + rowm;
        if constexpr (EPI == 0) {
            float ss = v4.x * v4.x + v4.y * v4.y + v4.z * v4.z + v4.w * v4.w;
            #pragma unroll
            for (int mm = 1; mm < 32; mm <<= 1) ss += __shfl_xor(ss, mm);
            float rs = 1.0f / sqrtf(fmaxf(ss, 1e-12f));
            int b = r >> 12, t = r & 4095;
            int h = n0 >> 7;                      // tile spans exactly one head
            size_t base = ((size_t)(b * NHEADS + h) * T_LEN + t) * DH + c4;
            unsigned h01 = cvtpk(v4.x, v4.y), h23 = cvtpk(v4.z, v4.w);
            float l0 = v4.x - bfu_lo(h01), l1 = v4.y - bfu_hi(h01);
            float l2 = v4.z - bfu_lo(h23), l3 = v4.w - bfu_hi(h23);
            *reinterpret_cast<uint2*>((__hip_bfloat16*)o1v + base) = make_uint2(h01, h23);
            *reinterpret_cast<uint2*>((__hip_bfloat16*)o2v + base) =
                make_uint2(cvtpk(l0, l1), cvtpk(l2, l3));
            if ((lin & 31) == 0)
                rsn[(size_t)(b * NHEADS + h) * T_LEN + t] = rs;
        } else if constexpr (EPI == 1) {
            int b = r >> 12, t = r & 4095;
            int n = n0 + c4;
            int h = n >> 7, d = n & 127;
            size_t base = ((size_t)(b * NHEADS + h) * T_LEN + t) * DH + d;
            *reinterpret_cast<uint2*>((__hip_bfloat16*)o1v + base) =
                make_uint2(cvtpk(v4.x, v4.y), cvtpk(v4.z, v4.w));
        } else {
            int n = n0 + c4;
            float4 o;
            o.x = v4.x + bias[n + 0]; o.y = v4.y + bias[n + 1];
            o.z = v4.z + bias[n + 2]; o.w = v4.w + bias[n + 3];
            *reinterpret_cast<float4*>((float*)o1v + (size_t)r * 1024 + n) = o;
        }
    }
}

// ------------------------------------------------------------------
// H: MFMA hash. rotated[64 rows][256 (r,i)] = qk-tile @ rotT, split-bf16
// 3-term (same error class as f32 path; GAP=2e-3 ~ 17 sigma). Epilogue:
// per (row, round) serial top-2 argmax over 64 signed candidates in
// reference scan order (strict >, pos 0..31 then neg) -> bucket + flag.
// ------------------------------------------------------------------
__global__ __launch_bounds__(256, 2) void k_hash_mfma(
    const __hip_bfloat16* __restrict__ Xh_g, const __hip_bfloat16* __restrict__ Xl_g,
    const __hip_bfloat16* __restrict__ Wh_g, const __hip_bfloat16* __restrict__ Wl_g,
    unsigned* __restrict__ bucketArr, unsigned* __restrict__ counter,
    unsigned* __restrict__ flaglist)
{
    __shared__ char smem[81920];
    short* Wh = (short*)smem;              // [256][64] swz64 (later osc)
    short* Wl = (short*)(smem + 32768);
    short* Xh = (short*)(smem + 65536);    // [64][64] swz64
    short* Xl = (short*)(smem + 73728);

    const int tid = threadIdx.x;
    const int m0 = blockIdx.x * 64;
    const int wave = tid >> 6, lane = tid & 63;
    const int it = wave & 1, jt2 = wave >> 1;
    const int h5 = lane >> 5;
    const int m_loc = it * 32 + (lane & 31);

    f32x16 acc[4] = {};

    for (int ks = 0; ks < 2; ++ks) {
        const int k0 = ks * 64;
        __syncthreads();
        for (int u = tid; u < 512; u += 256) {
            int row = u >> 3, blk = u & 7;
            size_t src = (size_t)(m0 + row) * 128 + k0 + blk * 8;
            int dst = swz64(row, blk * 8);
            *reinterpret_cast<int4*>(&Xh[dst]) = *reinterpret_cast<const int4*>(Xh_g + src);
            *reinterpret_cast<int4*>(&Xl[dst]) = *reinterpret_cast<const int4*>(Xl_g + src);
        }
        for (int u = tid; u < 2048; u += 256) {
            int row = u >> 3, blk = u & 7;
            size_t src = (size_t)row * 128 + k0 + blk * 8;
            int dst = swz64(row, blk * 8);
            *reinterpret_cast<int4*>(&Wh[dst]) = *reinterpret_cast<const int4*>(Wh_g + src);
            *reinterpret_cast<int4*>(&Wl[dst]) = *reinterpret_cast<const int4*>(Wl_g + src);
        }
        __syncthreads();

        #pragma unroll
        for (int kt = 0; kt < 4; ++kt) {
            int xoff = swz64(m_loc, kt * 16 + h5 * 8);
            short8 xfh = *reinterpret_cast<const short8*>(&Xh[xoff]);
            short8 xfl = *reinterpret_cast<const short8*>(&Xl[xoff]);
            #pragma unroll
            for (int jj = 0; jj < 4; ++jj) {
                int rowN = (jt2 * 4 + jj) * 32 + (lane & 31);
                int woff = swz64(rowN, kt * 16 + h5 * 8);
                short8 wfh = *reinterpret_cast<const short8*>(&Wh[woff]);
                short8 wfl = *reinterpret_cast<const short8*>(&Wl[woff]);
                acc[jj] = __builtin_amdgcn_mfma_f32_32x32x16_bf16(wfh, xfh, acc[jj], 0, 0, 0);
                acc[jj] = __builtin_amdgcn_mfma_f32_32x32x16_bf16(wfl, xfh, acc[jj], 0, 0, 0);
                acc[jj] = __builtin_amdgcn_mfma_f32_32x32x16_bf16(wfh, xfl, acc[jj], 0, 0, 0);
            }
        }
    }
    __syncthreads();

    // C^T -> osc[64 m][256 n] f32 (aliases Wh/Wl), XOR-swizzled
    float* osc = (float*)smem;
    #pragma unroll
    for (int jj = 0; jj < 4; ++jj) {
        int jt = jt2 * 4 + jj;
        #pragma unroll
        for (int r2 = 0; r2 < 16; ++r2) {
            int n = jt * 32 + (r2 & 3) + ((r2 >> 2) << 3) + (h5 << 2);
            osc[m_loc * 256 + (n ^ (m_loc & 28))] = acc[jj][r2];
        }
    }
    __syncthreads();

    // per (row, round): argmax + top-2 over {C_i} U {-C_i}, ref scan order
    #pragma unroll
    for (int p = 0; p < 2; ++p) {
        int pair = tid * 2 + p;            // 512 pairs
        int row = pair >> 3, r = pair & 7;
        float best = -1e30f, second = -1e30f;
        int bi = 0;
        for (int i = 0; i < 32; ++i) {
            float cv = osc[row * 256 + ((r * 32 + i) ^ (row & 28))];
            if (cv > best) { second = best; best = cv; bi = i; }
            else if (cv > second) second = cv;
        }
        for (int i = 0; i < 32; ++i) {
            float cv = -osc[row * 256 + ((r * 32 + i) ^ (row & 28))];
            if (cv > best) { second = best; best = cv; bi = i + 32; }
            else if (cv > second) second = cv;
        }
        int gr = m0 + row;
        int B = gr >> 12, t = gr & 4095;
        bucketArr[((size_t)B * NHASH + r) * T_LEN + t] = (unsigned)bi;
        if (best - second < GAP_THRESH) {
            unsigned pp = atomicAdd(counter, 1u);
            if (pp < FLAG_CAP)
                flaglist[pp] = ((unsigned)B << 15) | ((unsigned)r << 12) | (unsigned)t;
        }
    }
}

// ------------------------------------------------------------------
// K1c: exact f64 fixup for flagged near-tie argmaxes (proven r24).
// ------------------------------------------------------------------
__global__ __launch_bounds__(256) void k_fixup(
    const float* __restrict__ x, const float* __restrict__ wqk,
    const float* __restrict__ rot, const unsigned* __restrict__ counter,
    const unsigned* __restrict__ flaglist, unsigned* __restrict__ bucketArr)
{
    __shared__ float xsf[EMBD];
    __shared__ double qk64p[2][DH];
    __shared__ double vals[64];
    unsigned n = *counter;
    if (n > FLAG_CAP) n = FLAG_CAP;
    for (unsigned item = blockIdx.x; item < n; item += gridDim.x) {
        unsigned pk = flaglist[item];
        int t = pk & 4095, r = (pk >> 12) & 7, B = pk >> 15;
        int b = B >> 3, h = B & 7;
        reinterpret_cast<float4*>(xsf)[threadIdx.x] =
            reinterpret_cast<const float4*>(x + (size_t)(b * T_LEN + t) * EMBD)[threadIdx.x];
        __syncthreads();
        {
            int d = threadIdx.x & 127, gh = threadIdx.x >> 7;
            double a = 0.0;
            const float* wp = wqk + h * DH + d;
            const int e0 = gh << 9;
            for (int e = e0; e < e0 + 512; ++e)
                a = fma((double)xsf[e], (double)wp[(size_t)e * EMBD], a);
            qk64p[gh][d] = a;
        }
        __syncthreads();
        if (threadIdx.x < 32) {
            const float* rp = rot + r * 32 + threadIdx.x;
            double acc2 = 0.0;
            for (int f = 0; f < DH; ++f)
                acc2 = fma(qk64p[0][f] + qk64p[1][f], (double)rp[(size_t)f * 256], acc2);
            vals[threadIdx.x] = acc2;
            vals[threadIdx.x + 32] = -acc2;
        }
        __syncthreads();
        if (threadIdx.x == 0) {
            double best = vals[0]; int bi = 0;
            for (int u = 1; u < 64; ++u)
                if (vals[u] > best) { best = vals[u]; bi = u; }
            bucketArr[((size_t)B * NHASH + r) * T_LEN + t] = (unsigned)bi;
        }
        __syncthreads();
    }
}

// ------------------------------------------------------------------
// K3: stable counting sort per (B, hash-round) — unchanged (proven).
// ------------------------------------------------------------------
__global__ __launch_bounds__(64) void k_sort(
    const unsigned* __restrict__ bucketArr, unsigned* __restrict__ st)
{
    __shared__ unsigned short bkt[T_LEN];
    __shared__ unsigned hist[64][64];
    __shared__ unsigned bstart[64];
    const int B = blockIdx.x >> 3, r = blockIdx.x & 7;
    const unsigned* src = bucketArr + ((size_t)B * NHASH + r) * T_LEN;
    const int tid = threadIdx.x;

    for (int k = tid; k < T_LEN; k += 64) bkt[k] = (unsigned short)src[k];
    for (int k = tid; k < 64 * 64; k += 64) (&hist[0][0])[k] = 0;
    __syncthreads();
    {
        const int base = tid * 64;
        for (int k = 0; k < 64; ++k) hist[tid][bkt[base + k]]++;
    }
    __syncthreads();
    {
        unsigned tot = 0;
        for (int c = 0; c < 64; ++c) tot += hist[c][tid];
        bstart[tid] = tot;
    }
    __syncthreads();
    if (tid == 0) {
        unsigned run = 0;
        for (int q = 0; q < 64; ++q) { unsigned c = bstart[q]; bstart[q] = run; run += c; }
    }
    __syncthreads();
    {
        unsigned run = bstart[tid];
        for (int c = 0; c < 64; ++c) { unsigned h = hist[c][tid]; hist[c][tid] = run; run += h; }
    }
    __syncthreads();
    {
        unsigned* dst = st + ((size_t)B * NHASH + r) * T_LEN;
        const int base = tid * 64;
        for (int k = 0; k < 64; ++k) {
            unsigned bb2 = bkt[base + k];
            unsigned p = hist[tid][bb2]++;
            dst[p] = (unsigned)(base + k);
        }
    }
}

// ------------------------------------------------------------------
// K4: per-bin attention, ONE PASS per hash round — unchanged (proven).
// ------------------------------------------------------------------
__global__ __launch_bounds__(256, 3) void k_bin_pv(
    const __hip_bfloat16* __restrict__ qkh, const __hip_bfloat16* __restrict__ qkl,
    const __hip_bfloat16* __restrict__ vb, const float* __restrict__ rsn,
    const unsigned* __restrict__ st, float* __restrict__ Mbuf,
    float* __restrict__ Sbuf, float* __restrict__ attn, int rnd)
{
    __shared__ short Kh[128 * 128];        // K_hi -> V^T -> osc f32[64][128]
    __shared__ unsigned short Pb[64 * 128];// P bf16: [(j>>1)][i][j&1], 16 KB
    __shared__ int ktok[128];
    __shared__ float rs_l[128];
    __shared__ float red4b[2][2][2][32];   // [it][jt2][h5][col]
    __shared__ float mrow[64];
    __shared__ float abrow[64][2];         // per-query (a, b) weights

    const int tid = threadIdx.x;
    const int c = blockIdx.x & 63;
    const int B = blockIdx.x >> 6;
    const unsigned* stp = st + ((size_t)B * NHASH + rnd) * T_LEN;

    if (tid < 128) {
        int cc = (tid < 64) ? c : (c == 0 ? 1 : c - 1);
        int tok = (int)stp[cc * 64 + (tid & 63)];
        ktok[tid] = tok;
        rs_l[tid] = rsn[(size_t)B * T_LEN + tok];
    }
    __syncthreads();

    // stage K_hi (swizzled)
    for (int u = tid; u < 128 * 16; u += 256) {
        int row = u >> 4, blk = u & 15;
        *reinterpret_cast<int4*>(&Kh[swz(row, blk * 8)]) =
            *reinterpret_cast<const int4*>(qkh + ((size_t)B * T_LEN + ktok[row]) * DH + blk * 8);
    }

    const int wave = tid >> 6, lane = tid & 63;
    const int it = wave & 1, jt2 = wave >> 1;
    const int h5 = lane >> 5;
    const int i_loc = it * 32 + (lane & 31);
    const int qtok_i = ktok[i_loc];
    short8 qfh[8], qfl[8];
    {
        size_t qoff = ((size_t)B * T_LEN + qtok_i) * DH + (h5 << 3);
        #pragma unroll
        for (int kt = 0; kt < 8; ++kt) {
            qfh[kt] = *reinterpret_cast<const short8*>(qkh + qoff + kt * 16);
            qfl[kt] = *reinterpret_cast<const short8*>(qkl + qoff + kt * 16);
        }
    }
    __syncthreads();

    const float scale = 0.08838834764831845f;
    float p2[2][16];   // raw masked dots, then P
    #pragma unroll
    for (int jj = 0; jj < 2; ++jj) {
        int jt = jt2 * 2 + jj;
        f32x16 acc = {};
        #pragma unroll
        for (int kt = 0; kt < 8; ++kt) {        // FULL K, 2-term split S
            int so = swz(jt * 32 + (lane & 31), kt * 16 + (h5 << 3));
            short8 afh = *reinterpret_cast<const short8*>(&Kh[so]);
            acc = __builtin_amdgcn_mfma_f32_32x32x16_bf16(afh, qfh[kt], acc, 0, 0, 0);
            acc = __builtin_amdgcn_mfma_f32_32x32x16_bf16(afh, qfl[kt], acc, 0, 0, 0);
        }
        #pragma unroll
        for (int r2 = 0; r2 < 16; ++r2) {
            int jl = (r2 & 3) + ((r2 >> 2) << 3) + (h5 << 2);
            int jf = jt * 32 + jl;
            float s = acc[r2] * (scale * rs_l[jf]);
            p2[jj][r2] = (ktok[jf] == qtok_i) ? -1e5f : s;
        }
    }

    // ---- per-query max over 128 keys ----
    float mloc = p2[0][0];
    #pragma unroll
    for (int jj = 0; jj < 2; ++jj)
        #pragma unroll
        for (int r2 = 0; r2 < 16; ++r2) mloc = fmaxf(mloc, p2[jj][r2]);
    red4b[it][jt2][h5][lane & 31] = mloc;
    __syncthreads();                       // also: all Kh dot-reads done
    if (tid < 64) {
        int it2 = tid >> 5, i = tid & 31;
        mrow[tid] = fmaxf(fmaxf(red4b[it2][0][0][i], red4b[it2][0][1][i]),
                          fmaxf(red4b[it2][1][0][i], red4b[it2][1][1][i]));
    }
    __syncthreads();

    // ---- P = exp(S - m); per-query sum ----
    const float mi = mrow[i_loc];
    float sloc = 0.f;
    #pragma unroll
    for (int jj = 0; jj < 2; ++jj)
        #pragma unroll
        for (int r2 = 0; r2 < 16; ++r2) {
            float p = __expf(p2[jj][r2] - mi);
            p2[jj][r2] = p;
            sloc += p;
        }
    red4b[it][jt2][h5][lane & 31] = sloc;
    __syncthreads();

    // ---- s-merge + global M/S update; write Pb; stage V^T into Kh ----
    if (tid < 64) {
        int it2 = tid >> 5, i = tid & 31;
        float sr = red4b[it2][0][0][i] + red4b[it2][0][1][i] +
                   red4b[it2][1][0][i] + red4b[it2][1][1][i];
        float m = mrow[tid];
        size_t gi = (size_t)B * T_LEN + ktok[tid];
        float aw, bw;
        if (rnd == 0) {
            Mbuf[gi] = m; Sbuf[gi] = sr;
            aw = 0.f; bw = 1.f;
        } else {
            float Mold = Mbuf[gi];
            float Mnew = fmaxf(Mold, m);
            aw = __expf(Mold - Mnew);
            bw = __expf(m - Mnew);
            Sbuf[gi] = Sbuf[gi] * aw + sr * bw;
            Mbuf[gi] = Mnew;
        }
        abrow[tid][0] = aw; abrow[tid][1] = bw;
    }
    // P -> bf16 pairs: quadruple q covers rows 8q+4h5+{0..3} at col i_loc
    #pragma unroll
    for (int jj = 0; jj < 2; ++jj) {
        int jt = jt2 * 2 + jj;
        #pragma unroll
        for (int q = 0; q < 4; ++q) {
            int jhalf = jt * 16 + 4 * q + 2 * h5;   // (row>>1), row even
            unsigned pk0 = cvtpk(p2[jj][4 * q + 0], p2[jj][4 * q + 1]);
            unsigned pk1 = cvtpk(p2[jj][4 * q + 2], p2[jj][4 * q + 3]);
            *reinterpret_cast<unsigned*>(&Pb[jhalf * 128 + i_loc * 2]) = pk0;
            *reinterpret_cast<unsigned*>(&Pb[(jhalf + 1) * 128 + i_loc * 2]) = pk1;
        }
    }
    // restage Kh region as V^T (swizzled rows of V^T: row=d, col=j)
    {
        int j2 = tid >> 1, dbase = (tid & 1) * 64;
        const __hip_bfloat16* vrow = vb + ((size_t)B * T_LEN + ktok[j2]) * DH + dbase;
        #pragma unroll
        for (int mch = 0; mch < 8; ++mch) {
            short8 vv = *reinterpret_cast<const short8*>(vrow + mch * 8);
            #pragma unroll
            for (int e = 0; e < 8; ++e)
                Kh[swz(dbase + mch * 8 + e, j2)] = vv[e];
        }
    }
    __syncthreads();

    // MFMA PV: B-frags read directly from Pb (4 u32 each); A = V^T tiles.
    f32x16 oacc[4] = {};
    #pragma unroll
    for (int jj = 0; jj < 2; ++jj) {
        int jt = jt2 * 2 + jj;
        #pragma unroll
        for (int ks = 0; ks < 2; ++ks) {
            int jb0 = jt * 32 + ks * 16 + h5 * 8;   // even
            union Pack { unsigned u[4]; short8 v; } ph;
            #pragma unroll
            for (int m = 0; m < 4; ++m)
                ph.u[m] = *reinterpret_cast<const unsigned*>(
                    &Pb[((jb0 >> 1) + m) * 128 + i_loc * 2]);
            #pragma unroll
            for (int dt = 0; dt < 4; ++dt) {
                short8 af = *reinterpret_cast<const short8*>(
                    &Kh[swz(dt * 32 + (lane & 31), jb0)]);
                oacc[dt] = __builtin_amdgcn_mfma_f32_32x32x16_bf16(af, ph.v, oacc[dt], 0, 0, 0);
            }
        }
    }
    __syncthreads();   // done reading Pb and V^T(Kh)

    // combine jt2 halves in osc[64][128] f32 (Kh region, XOR-swizzled)
    float* osc = reinterpret_cast<float*>(Kh);
    if (jt2 == 1) {
        #pragma unroll
        for (int dt = 0; dt < 4; ++dt)
            #pragma unroll
            for (int r2 = 0; r2 < 16; ++r2) {
                int d = dt * 32 + (r2 & 3) + ((r2 >> 2) << 3) + (h5 << 2);
                osc[i_loc * 128 + (d ^ (i_loc & 28))] = oacc[dt][r2];
            }
    }
    __syncthreads();
    if (jt2 == 0) {
        #pragma unroll
        for (int dt = 0; dt < 4; ++dt)
            #pragma unroll
            for (int r2 = 0; r2 < 16; ++r2) {
                int d = dt * 32 + (r2 & 3) + ((r2 >> 2) << 3) + (h5 << 2);
                int a = i_loc * 128 + (d ^ (i_loc & 28));
                osc[a] += oacc[dt][r2];
            }
    }
    __syncthreads();

    // online-combined write: rnd 0 stores o_r; rnd>0: attn*a + o_r*b.
    #pragma unroll
    for (int w = 0; w < 8; ++w) {
        int lin = w * 256 + tid;          // float4 index over 64×32
        int rowq = lin >> 5;
        int d0 = (lin & 31) * 4;
        float4 sv4 = *reinterpret_cast<float4*>(&osc[rowq * 128 + (d0 ^ (rowq & 28))]);
        float* gp = attn + ((size_t)B * T_LEN + ktok[rowq]) * DH + d0;
        if (rnd == 0) {
            *reinterpret_cast<float4*>(gp) = sv4;
        } else {
            float aw = abrow[rowq][0], bw = abrow[rowq][1];
            float4 g = *reinterpret_cast<float4*>(gp);
            g.x = g.x * aw + sv4.x * bw;
            g.y = g.y * aw + sv4.y * bw;
            g.z = g.z * aw + sv4.z * bw;
            g.w = g.w * aw + sv4.w * bw;
            *reinterpret_cast<float4*>(gp) = g;
        }
    }
}

// ------------------------------------------------------------------
extern "C" void kernel_launch(void* const* d_in, const int* in_sizes, int n_in,
                              void* d_out, int out_size, void* d_ws, size_t ws_size,
                              hipStream_t stream)
{
    const float* x    = (const float*)d_in[0];
    const float* wqk  = (const float*)d_in[1];
    const float* wv   = (const float*)d_in[2];
    const float* wout = (const float*)d_in[3];
    const float* bout = (const float*)d_in[4];
    const float* rot  = (const float*)d_in[5];
    float* out = (float*)d_out;

    // ws layout (~103.7 MB; r23/r24 proved >= 103.6 MB usable):
    char* ws = (char*)d_ws;
    __hip_bfloat16* qkh       = (__hip_bfloat16*)(ws);
    __hip_bfloat16* qkl       = (__hip_bfloat16*)(ws + 16777216);
    __hip_bfloat16* vb        = (__hip_bfloat16*)(ws + 33554432);
    float*          attn      = (float*)        (ws + 50331648);
    __hip_bfloat16* xh        = (__hip_bfloat16*)(ws + 50331648);
    __hip_bfloat16* xl        = (__hip_bfloat16*)(ws + 67108864);
    unsigned*       bucketArr = (unsigned*)     (ws + 83886080);
    unsigned*       st        = (unsigned*)     (ws + 85983232);
    float*          Mbuf      = (float*)        (ws + 88080384);
    float*          Sbuf      = (float*)        (ws + 88342528);
    float*          rsn       = (float*)        (ws + 90439680);
    unsigned*       counter   = (unsigned*)     (ws + 90701824);
    unsigned*       flaglist  = (unsigned*)     (ws + 90705920);
    __hip_bfloat16* wT        = (__hip_bfloat16*)(ws + 90968064);   // 12.6 MB
    __hip_bfloat16* rotTh     = (__hip_bfloat16*)(ws + 103550976);  // 64 KB
    __hip_bfloat16* rotTl     = (__hip_bfloat16*)(ws + 103616512);  // 64 KB
    __hip_bfloat16* ah        = qkh;   // alias, used after pv
    __hip_bfloat16* al        = qkl;

    hipMemsetAsync(counter, 0, 4, stream);
    k_prep_x<<<2048, 256, 0, stream>>>(x, xh, xl);
    k_prep_w<<<768, 256, 0, stream>>>(wqk, wv, wout, wT);
    k_prep_rot<<<32, 256, 0, stream>>>(rot, rotTh, rotTl);
    k_gemm<0><<<1024, 256, 0, stream>>>(xh, xl, wT, wT + 1048576,
                                        qkh, qkl, rsn, nullptr);
    k_gemm<1><<<1024, 256, 0, stream>>>(xh, xl, wT + 2097152, wT + 3145728,
                                        vb, nullptr, nullptr, nullptr);
    k_hash_mfma<<<1024, 256, 0, stream>>>(qkh, qkl, rotTh, rotTl,
                                          bucketArr, counter, flaglist);
    k_fixup<<<1024, 256, 0, stream>>>(x, wqk, rot, counter, flaglist, bucketArr);
    k_sort<<<128, 64, 0, stream>>>(bucketArr, st);
    for (int r = 0; r < NHASH; ++r)
        k_bin_pv<<<1024, 256, 0, stream>>>(qkh, qkl, vb, rsn, st, Mbuf, Sbuf, attn, r);
    k_prep_a<<<2048, 256, 0, stream>>>(attn, Sbuf, ah, al);
    k_gemm<2><<<1024, 256, 0, stream>>>(ah, al, wT + 4194304, wT + 5242880,
                                        out, nullptr, nullptr, bout);
}